// Round 1
// baseline (36352.286 us; speedup 1.0000x reference)
//
#include <hip/hip_runtime.h>
#include <cstdint>
#include <cstddef>

// Problem constants (fixed by setup_inputs in the reference)
#define Bc   1024
#define NIFc 2048
#define Vc   10000
#define Ec   512
#define Hc   1024
#define Lc   32
#define NDc  3
#define G4c  4096   // 4*H

// ---------------------------------------------------------------------------
// Generic fp32 GEMM:  C[M,N] = A[M,K] @ W[N,K]^T (+ bias[N]) (+= C if acc)
// 64x64 tile, 256 threads, 4x4 microtile, TK=16, padded LDS (conflict-free).
// M must be a multiple of 64 (always 1024 here); N,K arbitrary-ish (K%16==0).
// ---------------------------------------------------------------------------
#define TM 64
#define TN 64
#define TK 16

__global__ __launch_bounds__(256) void gemm_tn(
    const float* __restrict__ A, const float* __restrict__ W,
    const float* __restrict__ bias, float* __restrict__ C,
    int M, int N, int K, int accumulate)
{
    __shared__ float As[TM][TK + 1];
    __shared__ float Ws[TN][TK + 1];
    const int tid = threadIdx.x;
    const int tx = tid & 15, ty = tid >> 4;
    const int m0 = blockIdx.y * TM, n0 = blockIdx.x * TN;
    float acc[4][4] = {};
    for (int k0 = 0; k0 < K; k0 += TK) {
        #pragma unroll
        for (int i = 0; i < 4; ++i) {
            int l = tid + i * 256;
            int kk = l & (TK - 1), mm = l >> 4;
            As[mm][kk] = A[(size_t)(m0 + mm) * K + k0 + kk];
        }
        #pragma unroll
        for (int i = 0; i < 4; ++i) {
            int l = tid + i * 256;
            int kk = l & (TK - 1), nn = l >> 4;
            int n = n0 + nn;
            Ws[nn][kk] = (n < N) ? W[(size_t)n * K + k0 + kk] : 0.0f;
        }
        __syncthreads();
        #pragma unroll
        for (int kk = 0; kk < TK; ++kk) {
            float a[4], b[4];
            #pragma unroll
            for (int i = 0; i < 4; ++i) a[i] = As[ty + 16 * i][kk];
            #pragma unroll
            for (int j = 0; j < 4; ++j) b[j] = Ws[tx + 16 * j][kk];
            #pragma unroll
            for (int i = 0; i < 4; ++i)
                #pragma unroll
                for (int j = 0; j < 4; ++j)
                    acc[i][j] = fmaf(a[i], b[j], acc[i][j]);
        }
        __syncthreads();
    }
    #pragma unroll
    for (int i = 0; i < 4; ++i) {
        int m = m0 + ty + 16 * i;
        #pragma unroll
        for (int j = 0; j < 4; ++j) {
            int n = n0 + tx + 16 * j;
            if (n < N) {
                float v = acc[i][j];
                if (bias) v += bias[n];
                size_t off = (size_t)m * N + n;
                if (accumulate) v += C[off];
                C[off] = v;
            }
        }
    }
}

// ---------------------------------------------------------------------------
// LSTM pointwise: gates [B,4H] in (i,f,g,o) chunk order -> update h,c in place
// ---------------------------------------------------------------------------
__global__ __launch_bounds__(256) void lstm_cell_kernel(
    const float* __restrict__ gates, float* __restrict__ h,
    float* __restrict__ c, int BH, int Hdim)
{
    int i = blockIdx.x * 256 + threadIdx.x;
    if (i >= BH) return;
    int b = i / Hdim, j = i - b * Hdim;
    const float* g = gates + (size_t)b * 4 * Hdim;
    float gi = g[j];
    float gf = g[Hdim + j];
    float gg = g[2 * Hdim + j];
    float go = g[3 * Hdim + j];
    float si = 1.0f / (1.0f + expf(-gi));
    float sf = 1.0f / (1.0f + expf(-gf));
    float so = 1.0f / (1.0f + expf(-go));
    float cn = sf * c[i] + si * tanhf(gg);
    c[i] = cn;
    h[i] = so * tanhf(cn);
}

// ---------------------------------------------------------------------------
// Per-row argmax over V logits (first-index tiebreak); optionally logp of the
// argmax token: logp = -log(sum exp(l - max)).
// ---------------------------------------------------------------------------
__global__ __launch_bounds__(256) void argmax_logp_kernel(
    const float* __restrict__ logits, int* __restrict__ msg_t,
    float* __restrict__ logp, int V, int want_logp)
{
    int b = blockIdx.x;
    const float* row = logits + (size_t)b * V;
    int tid = threadIdx.x;
    float bm = -__builtin_inff();
    int bi = 0x7fffffff;
    for (int j = tid; j < V; j += 256) {
        float v = row[j];
        if (v > bm) { bm = v; bi = j; }   // j increases, so first-max kept
    }
    __shared__ float sv[256];
    __shared__ int   si[256];
    sv[tid] = bm; si[tid] = bi;
    __syncthreads();
    for (int s = 128; s > 0; s >>= 1) {
        if (tid < s) {
            float v2 = sv[tid + s]; int i2 = si[tid + s];
            if (v2 > sv[tid] || (v2 == sv[tid] && i2 < si[tid])) {
                sv[tid] = v2; si[tid] = i2;
            }
        }
        __syncthreads();
    }
    if (tid == 0) msg_t[b] = si[0];
    if (want_logp) {
        float m = sv[0];
        __syncthreads();   // all threads read sv[0] before it is reused
        float s = 0.0f;
        for (int j = tid; j < V; j += 256) s += expf(row[j] - m);
        sv[tid] = s;
        __syncthreads();
        for (int st = 128; st > 0; st >>= 1) {
            if (tid < st) sv[tid] += sv[tid + st];
            __syncthreads();
        }
        if (tid == 0) logp[b] = -logf(sv[0]);
    }
}

// ---------------------------------------------------------------------------
// Embedding gather: out[b, :] = emb[idx[b * stride], :]  (stride 0 = broadcast)
// ---------------------------------------------------------------------------
__global__ __launch_bounds__(256) void gather_emb(
    const float* __restrict__ emb, const int* __restrict__ idx, int idx_stride,
    float* __restrict__ out, int Brows, int Edim)
{
    int i = blockIdx.x * 256 + threadIdx.x;
    if (i >= Brows * Edim) return;
    int b = i / Edim, e = i - b * Edim;
    int t = idx[b * idx_stride];
    out[i] = emb[(size_t)t * Edim + e];
}

// ---------------------------------------------------------------------------
// Hinge loss partial reduction over the B x B similarity matrices.
// S layout: [4][B][B]; S0 = target·r, S1..3 = distractor_n·r.
// partial += sum_{i,j} logp[j] * sum_n relu(1 - S0[i,j] + Sn[i,j])
// ---------------------------------------------------------------------------
__global__ __launch_bounds__(256) void hinge_kernel(
    const float* __restrict__ S, const float* __restrict__ logp,
    float* __restrict__ partials, int Bn)
{
    int tid = threadIdx.x;
    int n = Bn * Bn;
    float acc = 0.0f;
    for (int idx = blockIdx.x * 256 + tid; idx < n; idx += gridDim.x * 256) {
        int j = idx & (Bn - 1);
        float s0 = S[idx];
        float l = fmaxf(0.0f, 1.0f - s0 + S[n + idx])
                + fmaxf(0.0f, 1.0f - s0 + S[2 * n + idx])
                + fmaxf(0.0f, 1.0f - s0 + S[3 * n + idx]);
        acc += l * logp[j];
    }
    __shared__ float sv[256];
    sv[tid] = acc;
    __syncthreads();
    for (int s = 128; s > 0; s >>= 1) {
        if (tid < s) sv[tid] += sv[tid + s];
        __syncthreads();
    }
    if (tid == 0) partials[blockIdx.x] = sv[0];
}

__global__ __launch_bounds__(256) void final_reduce_kernel(
    const float* __restrict__ partials, int np, float* __restrict__ out,
    float scale)
{
    int tid = threadIdx.x;
    float acc = 0.0f;
    for (int i = tid; i < np; i += 256) acc += partials[i];
    __shared__ float sv[256];
    sv[tid] = acc;
    __syncthreads();
    for (int s = 128; s > 0; s >>= 1) {
        if (tid < s) sv[tid] += sv[tid + s];
        __syncthreads();
    }
    if (tid == 0) out[0] = sv[0] * scale;
}

// ---------------------------------------------------------------------------
extern "C" void kernel_launch(void* const* d_in, const int* in_sizes, int n_in,
                              void* d_out, int out_size, void* d_ws, size_t ws_size,
                              hipStream_t stream)
{
    (void)in_sizes; (void)n_in; (void)out_size; (void)ws_size;

    const float* target  = (const float*)d_in[0];
    const float* distr   = (const float*)d_in[1];
    const int*   start_t = (const int*)d_in[2];
    // d_in[3] = max_sentence_length (fixed 32, hardcoded)
    const float* W_aff = (const float*)d_in[4];
    const float* b_aff = (const float*)d_in[5];
    const float* emb_s = (const float*)d_in[6];
    const float* Wih_s = (const float*)d_in[7];
    const float* Whh_s = (const float*)d_in[8];
    const float* bih_s = (const float*)d_in[9];
    const float* bhh_s = (const float*)d_in[10];
    const float* Wp    = (const float*)d_in[11];
    const float* bp    = (const float*)d_in[12];
    const float* emb_r = (const float*)d_in[13];
    const float* Wih_r = (const float*)d_in[14];
    const float* Whh_r = (const float*)d_in[15];
    const float* bih_r = (const float*)d_in[16];
    const float* bhh_r = (const float*)d_in[17];
    const float* W_out = (const float*)d_in[18];
    const float* b_out = (const float*)d_in[19];

    // ---- workspace layout (floats) ----
    float* ws = (float*)d_ws;
    size_t o = 0;
    float* h_s    = ws + o; o += (size_t)Bc * Hc;        // 1M
    float* c_s    = ws + o; o += (size_t)Bc * Hc;        // 1M
    float* wv     = ws + o; o += (size_t)Bc * Ec;        // 0.5M
    float* gates  = ws + o; o += (size_t)Bc * G4c;       // 4M
    float* big    = ws + o; o += (size_t)Bc * Vc;        // 10.24M (logits; later r+S)
    float* logp   = ws + o; o += Bc;
    float* hr     = ws + o; o += (size_t)Bc * Hc;
    float* cr     = ws + o; o += (size_t)Bc * Hc;
    float* parts  = ws + o; o += 1024;
    int*   msg    = (int*)(ws + o);                      // L*B ints

    float* logits = big;
    float* r_vec  = big;                 // reuse after sender loop
    float* S      = big + (size_t)Bc * NIFc;  // 4*B*B floats, fits in big

    dim3 blk(256);
    const int gM = Bc / TM;  // 16

    // ---- Sender init ----
    // h0 = target @ W_aff^T + b_aff
    gemm_tn<<<dim3(Hc / TN, gM), blk, 0, stream>>>(target, W_aff, b_aff, h_s,
                                                   Bc, Hc, NIFc, 0);
    hipMemsetAsync(c_s, 0, (size_t)Bc * Hc * sizeof(float), stream);
    // w0 = emb_s[start_token] (broadcast)
    gather_emb<<<(Bc * Ec + 255) / 256, blk, 0, stream>>>(emb_s, start_t, 0, wv,
                                                          Bc, Ec);

    // ---- Sender greedy decode ----
    for (int t = 0; t < Lc; ++t) {
        gemm_tn<<<dim3(G4c / TN, gM), blk, 0, stream>>>(wv, Wih_s, bih_s, gates,
                                                        Bc, G4c, Ec, 0);
        gemm_tn<<<dim3(G4c / TN, gM), blk, 0, stream>>>(h_s, Whh_s, bhh_s, gates,
                                                        Bc, G4c, Hc, 1);
        lstm_cell_kernel<<<(Bc * Hc + 255) / 256, blk, 0, stream>>>(gates, h_s,
                                                                    c_s, Bc * Hc, Hc);
        gemm_tn<<<dim3((Vc + TN - 1) / TN, gM), blk, 0, stream>>>(h_s, Wp, bp,
                                                                  logits, Bc, Vc, Hc, 0);
        argmax_logp_kernel<<<Bc, blk, 0, stream>>>(logits, msg + t * Bc, logp,
                                                   Vc, (t == Lc - 1) ? 1 : 0);
        if (t < Lc - 1)
            gather_emb<<<(Bc * Ec + 255) / 256, blk, 0, stream>>>(
                emb_s, msg + t * Bc, 1, wv, Bc, Ec);
    }

    // ---- Receiver ----
    hipMemsetAsync(hr, 0, (size_t)Bc * Hc * sizeof(float), stream);
    hipMemsetAsync(cr, 0, (size_t)Bc * Hc * sizeof(float), stream);
    for (int t = 0; t < Lc; ++t) {
        gather_emb<<<(Bc * Ec + 255) / 256, blk, 0, stream>>>(
            emb_r, msg + t * Bc, 1, wv, Bc, Ec);
        gemm_tn<<<dim3(G4c / TN, gM), blk, 0, stream>>>(wv, Wih_r, bih_r, gates,
                                                        Bc, G4c, Ec, 0);
        gemm_tn<<<dim3(G4c / TN, gM), blk, 0, stream>>>(hr, Whh_r, bhh_r, gates,
                                                        Bc, G4c, Hc, 1);
        lstm_cell_kernel<<<(Bc * Hc + 255) / 256, blk, 0, stream>>>(gates, hr,
                                                                    cr, Bc * Hc, Hc);
    }

    // r = hr @ W_out^T + b_out   [B, NIF]
    gemm_tn<<<dim3(NIFc / TN, gM), blk, 0, stream>>>(hr, W_out, b_out, r_vec,
                                                     Bc, NIFc, Hc, 0);

    // Similarities: S0 = target @ r^T, S1..3 = distractors[n] @ r^T
    gemm_tn<<<dim3(Bc / TN, gM), blk, 0, stream>>>(target, r_vec, nullptr,
                                                   S, Bc, Bc, NIFc, 0);
    for (int n = 0; n < NDc; ++n)
        gemm_tn<<<dim3(Bc / TN, gM), blk, 0, stream>>>(
            distr + (size_t)n * Bc * NIFc, r_vec, nullptr,
            S + (size_t)(n + 1) * Bc * Bc, Bc, Bc, NIFc, 0);

    // Hinge + weighted mean
    hinge_kernel<<<1024, blk, 0, stream>>>(S, logp, parts, Bc);
    final_reduce_kernel<<<1, blk, 0, stream>>>(parts, 1024, (float*)d_out,
                                               -1.0f / ((float)Bc * (float)Bc));
}

// Round 2
// 8593.231 us; speedup vs baseline: 4.2303x; 4.2303x over previous
//
#include <hip/hip_runtime.h>
#include <hip/hip_bf16.h>
#include <cstdint>
#include <cstddef>

// Problem constants (fixed by setup_inputs in the reference)
#define Bc   1024
#define NIFc 2048
#define Vc   10000
#define Ec   512
#define Hc   1024
#define Lc   32
#define NDc  3
#define G4c  4096   // 4*H

typedef __attribute__((ext_vector_type(4))) float f32x4;
typedef __attribute__((ext_vector_type(8))) short s16x8;

// ===========================================================================
// bf16 MFMA GEMM:  C[M,N] = A[M,K] @ W[N,K]^T (+ bias[N])
// 128x128 tile, BK=64 bf16, 256 threads (4 waves, 2x2), 4x4 MFMA 16x16x32
// per wave. global_load_lds width=16 staging with XOR-swizzled LDS chunk
// layout: logical 16B chunk (row m, q in [0,8)) stored at phys chunk
// m*8 + (q ^ (m&7)) -> fragment ds_read_b128 is 2-way bank aliased (free).
// Requirements: M % 128 == 0, K % 64 == 0, A/W rows 16B-aligned (lda, ldw
// even multiples of 8 elements). N arbitrary (staging rows clamped, stores
// guarded).
// ===========================================================================
#define GBM 128
#define GBN 128
#define GBK 64

__device__ __forceinline__ void gld_lds16(void* lds, const void* g) {
    __builtin_amdgcn_global_load_lds(
        (const __attribute__((address_space(1))) unsigned int*)g,
        (__attribute__((address_space(3))) unsigned int*)lds,
        16, 0, 0);
}

__global__ __launch_bounds__(256) void gemm_bf16_tn(
    const __hip_bfloat16* __restrict__ A, int lda,
    const __hip_bfloat16* __restrict__ W, int ldw,
    const float* __restrict__ bias, float* __restrict__ C,
    int M, int N, int K)
{
    __shared__ __align__(16) __hip_bfloat16 As[GBM * GBK];
    __shared__ __align__(16) __hip_bfloat16 Ws[GBN * GBK];

    const int tid  = threadIdx.x;
    const int lane = tid & 63;
    const int wave = tid >> 6;
    const int m0 = blockIdx.y * GBM;
    const int n0 = blockIdx.x * GBN;

    // staging pointers: thread t covers phys chunks {t, t+256, t+512, t+768}
    const __hip_bfloat16* ag[4];
    const __hip_bfloat16* wg[4];
    #pragma unroll
    for (int r = 0; r < 4; ++r) {
        int p = r * 256 + tid;
        int m = p >> 3;
        int q = (p & 7) ^ (m & 7);          // logical q stored at this phys slot
        ag[r] = A + (size_t)(m0 + m) * lda + q * 8;
        int wn = n0 + m; if (wn >= N) wn = N - 1;   // clamp (stores guarded)
        wg[r] = W + (size_t)wn * ldw + q * 8;
    }

    f32x4 acc[4][4];
    #pragma unroll
    for (int i = 0; i < 4; ++i)
        #pragma unroll
        for (int j = 0; j < 4; ++j)
            acc[i][j] = (f32x4)(0.0f);

    const int hm = (wave & 1) << 6;
    const int hn = (wave >> 1) << 6;
    const int lm = lane & 15;
    const int quad = lane >> 4;

    const int nk = K >> 6;
    for (int kt = 0; kt < nk; ++kt) {
        __syncthreads();                     // prev compute done with LDS
        #pragma unroll
        for (int r = 0; r < 4; ++r) {
            int ldsbase = (r * 256 + wave * 64) * 8;   // element index
            gld_lds16(As + ldsbase, ag[r]);
            gld_lds16(Ws + ldsbase, wg[r]);
            ag[r] += GBK;
            wg[r] += GBK;
        }
        __syncthreads();                     // drains vmcnt -> data in LDS
        #pragma unroll
        for (int c = 0; c < 2; ++c) {        // two 16x16x32 k-chunks
            s16x8 af[4], wf[4];
            int q = c * 4 + quad;
            #pragma unroll
            for (int i = 0; i < 4; ++i) {
                int m = hm + i * 16 + lm;
                af[i] = *(const s16x8*)(As + ((m << 3) + (q ^ (m & 7))) * 8);
                int n = hn + i * 16 + lm;
                wf[i] = *(const s16x8*)(Ws + ((n << 3) + (q ^ (n & 7))) * 8);
            }
            #pragma unroll
            for (int i = 0; i < 4; ++i)
                #pragma unroll
                for (int j = 0; j < 4; ++j)
                    acc[i][j] = __builtin_amdgcn_mfma_f32_16x16x32_bf16(
                        af[i], wf[j], acc[i][j], 0, 0, 0);
        }
    }

    // epilogue: C/D layout col=lane&15, row=quad*4+reg
    #pragma unroll
    for (int i = 0; i < 4; ++i) {
        int mbase = m0 + hm + i * 16 + quad * 4;
        #pragma unroll
        for (int j = 0; j < 4; ++j) {
            int n = n0 + hn + j * 16 + lm;
            if (n < N) {
                float bv = bias ? bias[n] : 0.0f;
                #pragma unroll
                for (int rr = 0; rr < 4; ++rr)
                    C[(size_t)(mbase + rr) * N + n] = acc[i][j][rr] + bv;
            }
        }
    }
}

// ===========================================================================
// Cast / split kernels
// x3 split trick: A3 = [A_hi | A_lo | A_hi], W3 = [W_hi | W_hi | W_lo]
// so plain bf16 GEMM over 3K computes A_hi*W_hi + A_lo*W_hi + A_hi*W_lo
// (residual ~2^-18 relative -> argmax-safe).
// ===========================================================================
__global__ __launch_bounds__(256) void split3_a_kernel(
    const float* __restrict__ in, int ldin,
    __hip_bfloat16* __restrict__ out, int ldo, int coff, int M, int K)
{
    int i = blockIdx.x * 256 + threadIdx.x;
    if (i >= M * K) return;
    int m = i / K, k = i - m * K;
    float v = in[(size_t)m * ldin + k];
    __hip_bfloat16 hi = __float2bfloat16(v);
    float lo = v - __bfloat162float(hi);
    __hip_bfloat16* row = out + (size_t)m * ldo + coff;
    row[k] = hi;
    row[K + k] = __float2bfloat16(lo);
    row[2 * K + k] = hi;
}

__global__ __launch_bounds__(256) void split3_w_kernel(
    const float* __restrict__ in, int ldin,
    __hip_bfloat16* __restrict__ out, int ldo, int coff, int M, int K)
{
    int i = blockIdx.x * 256 + threadIdx.x;
    if (i >= M * K) return;
    int m = i / K, k = i - m * K;
    float v = in[(size_t)m * ldin + k];
    __hip_bfloat16 hi = __float2bfloat16(v);
    float lo = v - __bfloat162float(hi);
    __hip_bfloat16* row = out + (size_t)m * ldo + coff;
    row[k] = hi;
    row[K + k] = hi;
    row[2 * K + k] = __float2bfloat16(lo);
}

__global__ __launch_bounds__(256) void cast2d_kernel(
    const float* __restrict__ in, int ldin,
    __hip_bfloat16* __restrict__ out, int ldo, int coff, int M, int K)
{
    int i = blockIdx.x * 256 + threadIdx.x;
    if (i >= M * K) return;
    int m = i / K, k = i - m * K;
    out[(size_t)m * ldo + coff + k] = __float2bfloat16(in[(size_t)m * ldin + k]);
}

// gather emb rows by token idx with x3 split (sender input)
__global__ __launch_bounds__(256) void gather_split3_kernel(
    const float* __restrict__ emb, int E, const int* __restrict__ idx,
    int stride, __hip_bfloat16* __restrict__ out, int ldo, int Brows)
{
    int i = blockIdx.x * 256 + threadIdx.x;
    if (i >= Brows * E) return;
    int b = i / E, k = i - b * E;
    float v = emb[(size_t)idx[b * stride] * E + k];
    __hip_bfloat16 hi = __float2bfloat16(v);
    float lo = v - __bfloat162float(hi);
    __hip_bfloat16* row = out + (size_t)b * ldo;
    row[k] = hi;
    row[E + k] = __float2bfloat16(lo);
    row[2 * E + k] = hi;
}

// gather emb rows by token idx, plain bf16 (receiver input)
__global__ __launch_bounds__(256) void gather_cast_kernel(
    const float* __restrict__ emb, int E, const int* __restrict__ idx,
    __hip_bfloat16* __restrict__ out, int ldo, int coff, int Brows)
{
    int i = blockIdx.x * 256 + threadIdx.x;
    if (i >= Brows * E) return;
    int b = i / E, k = i - b * E;
    out[(size_t)b * ldo + coff + k] =
        __float2bfloat16(emb[(size_t)idx[b] * E + k]);
}

__global__ __launch_bounds__(256) void add_vec_kernel(
    const float* __restrict__ a, const float* __restrict__ b,
    float* __restrict__ o, int n)
{
    int i = blockIdx.x * 256 + threadIdx.x;
    if (i < n) o[i] = a[i] + b[i];
}

// ===========================================================================
// LSTM pointwise (gates [B,4H] chunk order i,f,g,o)
// ===========================================================================
__global__ __launch_bounds__(256) void lstm_cell_kernel(
    const float* __restrict__ gates, float* __restrict__ h,
    float* __restrict__ c, int BH, int Hdim)
{
    int i = blockIdx.x * 256 + threadIdx.x;
    if (i >= BH) return;
    int b = i / Hdim, j = i - b * Hdim;
    const float* g = gates + (size_t)b * 4 * Hdim;
    float gi = g[j];
    float gf = g[Hdim + j];
    float gg = g[2 * Hdim + j];
    float go = g[3 * Hdim + j];
    float si = 1.0f / (1.0f + expf(-gi));
    float sf = 1.0f / (1.0f + expf(-gf));
    float so = 1.0f / (1.0f + expf(-go));
    float cn = sf * c[i] + si * tanhf(gg);
    c[i] = cn;
    h[i] = so * tanhf(cn);
}

// ===========================================================================
// Row argmax (+ optional logp of argmax via logsumexp)
// ===========================================================================
__global__ __launch_bounds__(256) void argmax_logp_kernel(
    const float* __restrict__ logits, int* __restrict__ msg_t,
    float* __restrict__ logp, int V, int want_logp)
{
    int b = blockIdx.x;
    const float* row = logits + (size_t)b * V;
    int tid = threadIdx.x;
    float bm = -__builtin_inff();
    int bi = 0x7fffffff;
    for (int j = tid; j < V; j += 256) {
        float v = row[j];
        if (v > bm) { bm = v; bi = j; }
    }
    __shared__ float sv[256];
    __shared__ int   si[256];
    sv[tid] = bm; si[tid] = bi;
    __syncthreads();
    for (int s = 128; s > 0; s >>= 1) {
        if (tid < s) {
            float v2 = sv[tid + s]; int i2 = si[tid + s];
            if (v2 > sv[tid] || (v2 == sv[tid] && i2 < si[tid])) {
                sv[tid] = v2; si[tid] = i2;
            }
        }
        __syncthreads();
    }
    if (tid == 0) msg_t[b] = si[0];
    if (want_logp) {
        float m = sv[0];
        __syncthreads();
        float s = 0.0f;
        for (int j = tid; j < V; j += 256) s += expf(row[j] - m);
        sv[tid] = s;
        __syncthreads();
        for (int st = 128; st > 0; st >>= 1) {
            if (tid < st) sv[tid] += sv[tid + st];
            __syncthreads();
        }
        if (tid == 0) logp[b] = -logf(sv[0]);
    }
}

// ===========================================================================
// Hinge loss partial reduction; S layout [4][B][B], fast axis j weights logp
// ===========================================================================
__global__ __launch_bounds__(256) void hinge_kernel(
    const float* __restrict__ S, const float* __restrict__ logp,
    float* __restrict__ partials, int Bn)
{
    int tid = threadIdx.x;
    int n = Bn * Bn;
    float acc = 0.0f;
    for (int idx = blockIdx.x * 256 + tid; idx < n; idx += gridDim.x * 256) {
        int j = idx & (Bn - 1);
        float s0 = S[idx];
        float l = fmaxf(0.0f, 1.0f - s0 + S[n + idx])
                + fmaxf(0.0f, 1.0f - s0 + S[2 * n + idx])
                + fmaxf(0.0f, 1.0f - s0 + S[3 * n + idx]);
        acc += l * logp[j];
    }
    __shared__ float sv[256];
    sv[tid] = acc;
    __syncthreads();
    for (int s = 128; s > 0; s >>= 1) {
        if (tid < s) sv[tid] += sv[tid + s];
        __syncthreads();
    }
    if (tid == 0) partials[blockIdx.x] = sv[0];
}

__global__ __launch_bounds__(256) void final_reduce_kernel(
    const float* __restrict__ partials, int np, float* __restrict__ out,
    float scale)
{
    int tid = threadIdx.x;
    float acc = 0.0f;
    for (int i = tid; i < np; i += 256) acc += partials[i];
    __shared__ float sv[256];
    sv[tid] = acc;
    __syncthreads();
    for (int s = 128; s > 0; s >>= 1) {
        if (tid < s) sv[tid] += sv[tid + s];
        __syncthreads();
    }
    if (tid == 0) out[0] = sv[0] * scale;
}

// ===========================================================================
// Legacy fp32 GEMM path (fallback if workspace too small) — proven in R1
// ===========================================================================
#define TM 64
#define TN 64
#define TK 16

__global__ __launch_bounds__(256) void gemm_tn(
    const float* __restrict__ A, const float* __restrict__ W,
    const float* __restrict__ bias, float* __restrict__ C,
    int M, int N, int K, int accumulate)
{
    __shared__ float Asf[TM][TK + 1];
    __shared__ float Wsf[TN][TK + 1];
    const int tid = threadIdx.x;
    const int tx = tid & 15, ty = tid >> 4;
    const int m0 = blockIdx.y * TM, n0 = blockIdx.x * TN;
    float acc[4][4] = {};
    for (int k0 = 0; k0 < K; k0 += TK) {
        #pragma unroll
        for (int i = 0; i < 4; ++i) {
            int l = tid + i * 256;
            int kk = l & (TK - 1), mm = l >> 4;
            Asf[mm][kk] = A[(size_t)(m0 + mm) * K + k0 + kk];
        }
        #pragma unroll
        for (int i = 0; i < 4; ++i) {
            int l = tid + i * 256;
            int kk = l & (TK - 1), nn = l >> 4;
            int n = n0 + nn;
            Wsf[nn][kk] = (n < N) ? W[(size_t)n * K + k0 + kk] : 0.0f;
        }
        __syncthreads();
        #pragma unroll
        for (int kk = 0; kk < TK; ++kk) {
            float a[4], b[4];
            #pragma unroll
            for (int i = 0; i < 4; ++i) a[i] = Asf[ty + 16 * i][kk];
            #pragma unroll
            for (int j = 0; j < 4; ++j) b[j] = Wsf[tx + 16 * j][kk];
            #pragma unroll
            for (int i = 0; i < 4; ++i)
                #pragma unroll
                for (int j = 0; j < 4; ++j)
                    acc[i][j] = fmaf(a[i], b[j], acc[i][j]);
        }
        __syncthreads();
    }
    #pragma unroll
    for (int i = 0; i < 4; ++i) {
        int m = m0 + ty + 16 * i;
        #pragma unroll
        for (int j = 0; j < 4; ++j) {
            int n = n0 + tx + 16 * j;
            if (n < N) {
                float v = acc[i][j];
                if (bias) v += bias[n];
                size_t off = (size_t)m * N + n;
                if (accumulate) v += C[off];
                C[off] = v;
            }
        }
    }
}

__global__ __launch_bounds__(256) void gather_emb(
    const float* __restrict__ emb, const int* __restrict__ idx, int idx_stride,
    float* __restrict__ out, int Brows, int Edim)
{
    int i = blockIdx.x * 256 + threadIdx.x;
    if (i >= Brows * Edim) return;
    int b = i / Edim, e = i - b * Edim;
    int t = idx[b * idx_stride];
    out[i] = emb[(size_t)t * Edim + e];
}

// ===========================================================================
extern "C" void kernel_launch(void* const* d_in, const int* in_sizes, int n_in,
                              void* d_out, int out_size, void* d_ws, size_t ws_size,
                              hipStream_t stream)
{
    (void)in_sizes; (void)n_in; (void)out_size;

    const float* target  = (const float*)d_in[0];
    const float* distr   = (const float*)d_in[1];
    const int*   start_t = (const int*)d_in[2];
    const float* W_aff = (const float*)d_in[4];
    const float* b_aff = (const float*)d_in[5];
    const float* emb_s = (const float*)d_in[6];
    const float* Wih_s = (const float*)d_in[7];
    const float* Whh_s = (const float*)d_in[8];
    const float* bih_s = (const float*)d_in[9];
    const float* bhh_s = (const float*)d_in[10];
    const float* Wp    = (const float*)d_in[11];
    const float* bp    = (const float*)d_in[12];
    const float* emb_r = (const float*)d_in[13];
    const float* Wih_r = (const float*)d_in[14];
    const float* Whh_r = (const float*)d_in[15];
    const float* bih_r = (const float*)d_in[16];
    const float* bhh_r = (const float*)d_in[17];
    const float* W_out = (const float*)d_in[18];
    const float* b_out = (const float*)d_in[19];

    dim3 blk(256);

    // ---------------- big-path workspace layout (bytes) ----------------
    char* b0 = (char*)d_ws;
    size_t off = 0;
    auto take = [&](size_t bytes) -> char* {
        char* p = b0 + off;
        off += (bytes + 511) & ~(size_t)511;
        return p;
    };
    const size_t MB = 1024 * 1024;
    __hip_bfloat16* WihWhh3 = (__hip_bfloat16*)take((size_t)G4c * 4608 * 2);
    __hip_bfloat16* Wp3     = (__hip_bfloat16*)take((size_t)Vc * 3072 * 2);
    __hip_bfloat16* WihWhh_r= (__hip_bfloat16*)take((size_t)G4c * 1536 * 2);
    __hip_bfloat16* W_out_b = (__hip_bfloat16*)take((size_t)NIFc * Hc * 2);
    __hip_bfloat16* xh3     = (__hip_bfloat16*)take((size_t)Bc * 4608 * 2);
    __hip_bfloat16* xh_r    = (__hip_bfloat16*)take((size_t)Bc * 1536 * 2);
    float* gates  = (float*)take((size_t)Bc * G4c * 4);
    float* h_s    = (float*)take((size_t)Bc * Hc * 4);
    float* c_s    = (float*)take((size_t)Bc * Hc * 4);
    float* hr     = (float*)take((size_t)Bc * Hc * 4);
    float* cr     = (float*)take((size_t)Bc * Hc * 4);
    float* logp   = (float*)take(Bc * 4);
    int*   msg    = (int*)take((size_t)Lc * Bc * 4);
    float* parts  = (float*)take(1024 * 4);
    float* bias_s = (float*)take(G4c * 4);
    float* bias_r = (float*)take(G4c * 4);
    char*  U      = take(48 * MB);
    size_t need = off;

    // U sub-layout (phased reuse)
    __hip_bfloat16* target3 = (__hip_bfloat16*)U;                 // phase 1
    __hip_bfloat16* W_aff3  = (__hip_bfloat16*)(U + 13 * MB);     // phase 1
    float*          logits  = (float*)U;                          // phase 2
    __hip_bfloat16* A4b     = (__hip_bfloat16*)U;                 // phase 3
    float*          r_f     = (float*)(U + 17 * MB);              // phase 3
    __hip_bfloat16* r_b     = (__hip_bfloat16*)(U + 26 * MB);     // phase 3
    float*          S       = (float*)(U + 31 * MB);              // phase 3

    if (ws_size >= need) {
        // ================= bf16 MFMA path =================
        // ---- weight prep (once per launch) ----
        split3_w_kernel<<<(G4c * Ec + 255) / 256, blk, 0, stream>>>(
            Wih_s, Ec, WihWhh3, 4608, 0, G4c, Ec);
        split3_w_kernel<<<(G4c * Hc + 255) / 256, blk, 0, stream>>>(
            Whh_s, Hc, WihWhh3, 4608, 1536, G4c, Hc);
        split3_w_kernel<<<(Vc * Hc + 255) / 256, blk, 0, stream>>>(
            Wp, Hc, Wp3, 3072, 0, Vc, Hc);
        split3_a_kernel<<<(Bc * NIFc + 255) / 256, blk, 0, stream>>>(
            target, NIFc, target3, 6144, 0, Bc, NIFc);
        split3_w_kernel<<<(Hc * NIFc + 255) / 256, blk, 0, stream>>>(
            W_aff, NIFc, W_aff3, 6144, 0, Hc, NIFc);
        cast2d_kernel<<<(G4c * Ec + 255) / 256, blk, 0, stream>>>(
            Wih_r, Ec, WihWhh_r, 1536, 0, G4c, Ec);
        cast2d_kernel<<<(G4c * Hc + 255) / 256, blk, 0, stream>>>(
            Whh_r, Hc, WihWhh_r, 1536, Ec, G4c, Hc);
        cast2d_kernel<<<(NIFc * Hc + 255) / 256, blk, 0, stream>>>(
            W_out, Hc, W_out_b, Hc, 0, NIFc, Hc);
        add_vec_kernel<<<(G4c + 255) / 256, blk, 0, stream>>>(bih_s, bhh_s,
                                                              bias_s, G4c);
        add_vec_kernel<<<(G4c + 255) / 256, blk, 0, stream>>>(bih_r, bhh_r,
                                                              bias_r, G4c);

        // ---- sender init: h0 = target @ W_aff^T + b_aff (x3) ----
        gemm_bf16_tn<<<dim3(Hc / GBN, Bc / GBM), blk, 0, stream>>>(
            target3, 6144, W_aff3, 6144, b_aff, h_s, Bc, Hc, 6144);
        hipMemsetAsync(c_s, 0, (size_t)Bc * Hc * 4, stream);
        // w0 = emb_s[start] split into xh3 cols [0,1536)
        gather_split3_kernel<<<(Bc * Ec + 255) / 256, blk, 0, stream>>>(
            emb_s, Ec, start_t, 0, xh3, 4608, Bc);
        // h3 = split(h0) into xh3 cols [1536,4608)
        split3_a_kernel<<<(Bc * Hc + 255) / 256, blk, 0, stream>>>(
            h_s, Hc, xh3, 4608, 1536, Bc, Hc);

        // ---- sender greedy decode ----
        for (int t = 0; t < Lc; ++t) {
            // gates = [wv|h] @ [Wih|Whh]^T + (bih+bhh)   (x3, K=4608)
            gemm_bf16_tn<<<dim3(G4c / GBN, Bc / GBM), blk, 0, stream>>>(
                xh3, 4608, WihWhh3, 4608, bias_s, gates, Bc, G4c, 4608);
            lstm_cell_kernel<<<(Bc * Hc + 255) / 256, blk, 0, stream>>>(
                gates, h_s, c_s, Bc * Hc, Hc);
            split3_a_kernel<<<(Bc * Hc + 255) / 256, blk, 0, stream>>>(
                h_s, Hc, xh3, 4608, 1536, Bc, Hc);
            // logits = h @ Wp^T + bp   (x3, K=3072)
            gemm_bf16_tn<<<dim3((Vc + GBN - 1) / GBN, Bc / GBM), blk, 0, stream>>>(
                xh3 + 1536, 4608, Wp3, 3072, bp, logits, Bc, Vc, 3072);
            argmax_logp_kernel<<<Bc, blk, 0, stream>>>(
                logits, msg + t * Bc, logp, Vc, (t == Lc - 1) ? 1 : 0);
            if (t < Lc - 1)
                gather_split3_kernel<<<(Bc * Ec + 255) / 256, blk, 0, stream>>>(
                    emb_s, Ec, msg + t * Bc, 1, xh3, 4608, Bc);
        }

        // ---- receiver (plain bf16) ----
        hipMemsetAsync(hr, 0, (size_t)Bc * Hc * 4, stream);
        hipMemsetAsync(cr, 0, (size_t)Bc * Hc * 4, stream);
        hipMemsetAsync(xh_r, 0, (size_t)Bc * 1536 * 2, stream);  // h-region = 0
        for (int t = 0; t < Lc; ++t) {
            gather_cast_kernel<<<(Bc * Ec + 255) / 256, blk, 0, stream>>>(
                emb_r, Ec, msg + t * Bc, xh_r, 1536, 0, Bc);
            gemm_bf16_tn<<<dim3(G4c / GBN, Bc / GBM), blk, 0, stream>>>(
                xh_r, 1536, WihWhh_r, 1536, bias_r, gates, Bc, G4c, 1536);
            lstm_cell_kernel<<<(Bc * Hc + 255) / 256, blk, 0, stream>>>(
                gates, hr, cr, Bc * Hc, Hc);
            cast2d_kernel<<<(Bc * Hc + 255) / 256, blk, 0, stream>>>(
                hr, Hc, xh_r, 1536, Ec, Bc, Hc);
        }

        // ---- r = hr @ W_out^T + b_out ----
        gemm_bf16_tn<<<dim3(NIFc / GBN, Bc / GBM), blk, 0, stream>>>(
            xh_r + Ec, 1536, W_out_b, Hc, b_out, r_f, Bc, NIFc, Hc);

        // ---- similarities: [target; distractors] @ r^T in ONE GEMM ----
        cast2d_kernel<<<(Bc * NIFc + 255) / 256, blk, 0, stream>>>(
            target, NIFc, A4b, NIFc, 0, Bc, NIFc);
        cast2d_kernel<<<(NDc * Bc * NIFc + 255) / 256, blk, 0, stream>>>(
            distr, NIFc, A4b + (size_t)Bc * NIFc, NIFc, 0, NDc * Bc, NIFc);
        cast2d_kernel<<<(Bc * NIFc + 255) / 256, blk, 0, stream>>>(
            r_f, NIFc, r_b, NIFc, 0, Bc, NIFc);
        gemm_bf16_tn<<<dim3(Bc / GBN, 4 * Bc / GBM), blk, 0, stream>>>(
            A4b, NIFc, r_b, NIFc, nullptr, S, 4 * Bc, Bc, NIFc);

        hinge_kernel<<<1024, blk, 0, stream>>>(S, logp, parts, Bc);
        final_reduce_kernel<<<1, blk, 0, stream>>>(
            parts, 1024, (float*)d_out, -1.0f / ((float)Bc * (float)Bc));
        return;
    }

    // ================= legacy fp32 fallback (R1, proven) =================
    float* ws = (float*)d_ws;
    size_t o = 0;
    float* h_sf   = ws + o; o += (size_t)Bc * Hc;
    float* c_sf   = ws + o; o += (size_t)Bc * Hc;
    float* wv     = ws + o; o += (size_t)Bc * Ec;
    float* gatesf = ws + o; o += (size_t)Bc * G4c;
    float* big    = ws + o; o += (size_t)Bc * Vc;
    float* logpf  = ws + o; o += Bc;
    float* hrf    = ws + o; o += (size_t)Bc * Hc;
    float* crf    = ws + o; o += (size_t)Bc * Hc;
    float* partsf = ws + o; o += 1024;
    int*   msgf   = (int*)(ws + o);

    float* logitsf = big;
    float* r_vec   = big;
    float* Sf      = big + (size_t)Bc * NIFc;

    const int gM = Bc / TM;
    gemm_tn<<<dim3(Hc / TN, gM), blk, 0, stream>>>(target, W_aff, b_aff, h_sf,
                                                   Bc, Hc, NIFc, 0);
    hipMemsetAsync(c_sf, 0, (size_t)Bc * Hc * 4, stream);
    gather_emb<<<(Bc * Ec + 255) / 256, blk, 0, stream>>>(emb_s, start_t, 0,
                                                          wv, Bc, Ec);
    for (int t = 0; t < Lc; ++t) {
        gemm_tn<<<dim3(G4c / TN, gM), blk, 0, stream>>>(wv, Wih_s, bih_s,
                                                        gatesf, Bc, G4c, Ec, 0);
        gemm_tn<<<dim3(G4c / TN, gM), blk, 0, stream>>>(h_sf, Whh_s, bhh_s,
                                                        gatesf, Bc, G4c, Hc, 1);
        lstm_cell_kernel<<<(Bc * Hc + 255) / 256, blk, 0, stream>>>(
            gatesf, h_sf, c_sf, Bc * Hc, Hc);
        gemm_tn<<<dim3((Vc + TN - 1) / TN, gM), blk, 0, stream>>>(
            h_sf, Wp, bp, logitsf, Bc, Vc, Hc, 0);
        argmax_logp_kernel<<<Bc, blk, 0, stream>>>(logitsf, msgf + t * Bc,
                                                   logpf, Vc, (t == Lc - 1) ? 1 : 0);
        if (t < Lc - 1)
            gather_emb<<<(Bc * Ec + 255) / 256, blk, 0, stream>>>(
                emb_s, msgf + t * Bc, 1, wv, Bc, Ec);
    }
    hipMemsetAsync(hrf, 0, (size_t)Bc * Hc * 4, stream);
    hipMemsetAsync(crf, 0, (size_t)Bc * Hc * 4, stream);
    for (int t = 0; t < Lc; ++t) {
        gather_emb<<<(Bc * Ec + 255) / 256, blk, 0, stream>>>(
            emb_r, msgf + t * Bc, 1, wv, Bc, Ec);
        gemm_tn<<<dim3(G4c / TN, gM), blk, 0, stream>>>(wv, Wih_r, bih_r,
                                                        gatesf, Bc, G4c, Ec, 0);
        gemm_tn<<<dim3(G4c / TN, gM), blk, 0, stream>>>(hrf, Whh_r, bhh_r,
                                                        gatesf, Bc, G4c, Hc, 1);
        lstm_cell_kernel<<<(Bc * Hc + 255) / 256, blk, 0, stream>>>(
            gatesf, hrf, crf, Bc * Hc, Hc);
    }
    gemm_tn<<<dim3(NIFc / TN, gM), blk, 0, stream>>>(hrf, W_out, b_out, r_vec,
                                                     Bc, NIFc, Hc, 0);
    gemm_tn<<<dim3(Bc / TN, gM), blk, 0, stream>>>(target, r_vec, nullptr,
                                                   Sf, Bc, Bc, NIFc, 0);
    for (int n = 0; n < NDc; ++n)
        gemm_tn<<<dim3(Bc / TN, gM), blk, 0, stream>>>(
            distr + (size_t)n * Bc * NIFc, r_vec, nullptr,
            Sf + (size_t)(n + 1) * Bc * Bc, Bc, Bc, NIFc, 0);
    hinge_kernel<<<1024, blk, 0, stream>>>(Sf, logpf, partsf, Bc);
    final_reduce_kernel<<<1, blk, 0, stream>>>(partsf, 1024, (float*)d_out,
                                               -1.0f / ((float)Bc * (float)Bc));
}

// Round 3
// 8172.910 us; speedup vs baseline: 4.4479x; 1.0514x over previous
//
#include <hip/hip_runtime.h>
#include <hip/hip_bf16.h>
#include <cstdint>
#include <cstddef>

// Problem constants (fixed by setup_inputs in the reference)
#define Bc   1024
#define NIFc 2048
#define Vc   10000
#define Ec   512
#define Hc   1024
#define Lc   32
#define NDc  3
#define G4c  4096   // 4*H

typedef __attribute__((ext_vector_type(4))) float f32x4;
typedef __attribute__((ext_vector_type(8))) short s16x8;

// ===========================================================================
// bf16 MFMA GEMM body:  C[M,N] = A[M,K] @ W[N,K]^T (+ bias[N])
// 128x128 tile, BK=64 bf16, 256 threads (4 waves, 2x2), 4x4 MFMA 16x16x32
// per wave. global_load_lds width=16 staging with XOR-swizzled LDS chunk
// layout (phys chunk = m*8 + (q ^ (m&7))) -> ds_read_b128 fragment reads are
// 2-way bank aliased (free, m136). Reqs: M%128==0, K%64==0, rows 16B-aligned.
// ===========================================================================
#define GBM 128
#define GBN 128
#define GBK 64

__device__ __forceinline__ void gld_lds16(void* lds, const void* g) {
    __builtin_amdgcn_global_load_lds(
        (const __attribute__((address_space(1))) unsigned int*)g,
        (__attribute__((address_space(3))) unsigned int*)lds,
        16, 0, 0);
}

__device__ __forceinline__ void gemm_body(
    const __hip_bfloat16* __restrict__ A, int lda,
    const __hip_bfloat16* __restrict__ W, int ldw,
    const float* __restrict__ bias, float* __restrict__ C,
    int M, int N, int K, int bx, int by)
{
    __shared__ __align__(16) __hip_bfloat16 As[GBM * GBK];
    __shared__ __align__(16) __hip_bfloat16 Ws[GBN * GBK];

    const int tid  = threadIdx.x;
    const int lane = tid & 63;
    const int wave = tid >> 6;
    const int m0 = by * GBM;
    const int n0 = bx * GBN;

    const __hip_bfloat16* ag[4];
    const __hip_bfloat16* wg[4];
    #pragma unroll
    for (int r = 0; r < 4; ++r) {
        int p = r * 256 + tid;
        int m = p >> 3;
        int q = (p & 7) ^ (m & 7);
        ag[r] = A + (size_t)(m0 + m) * lda + q * 8;
        int wn = n0 + m; if (wn >= N) wn = N - 1;
        wg[r] = W + (size_t)wn * ldw + q * 8;
    }

    f32x4 acc[4][4];
    #pragma unroll
    for (int i = 0; i < 4; ++i)
        #pragma unroll
        for (int j = 0; j < 4; ++j)
            acc[i][j] = (f32x4)(0.0f);

    const int hm = (wave & 1) << 6;
    const int hn = (wave >> 1) << 6;
    const int lm = lane & 15;
    const int quad = lane >> 4;

    const int nk = K >> 6;
    for (int kt = 0; kt < nk; ++kt) {
        __syncthreads();
        #pragma unroll
        for (int r = 0; r < 4; ++r) {
            int ldsbase = (r * 256 + wave * 64) * 8;
            gld_lds16(As + ldsbase, ag[r]);
            gld_lds16(Ws + ldsbase, wg[r]);
            ag[r] += GBK;
            wg[r] += GBK;
        }
        __syncthreads();
        #pragma unroll
        for (int c = 0; c < 2; ++c) {
            s16x8 af[4], wf[4];
            int q = c * 4 + quad;
            #pragma unroll
            for (int i = 0; i < 4; ++i) {
                int m = hm + i * 16 + lm;
                af[i] = *(const s16x8*)(As + ((m << 3) + (q ^ (m & 7))) * 8);
                int n = hn + i * 16 + lm;
                wf[i] = *(const s16x8*)(Ws + ((n << 3) + (q ^ (n & 7))) * 8);
            }
            #pragma unroll
            for (int i = 0; i < 4; ++i)
                #pragma unroll
                for (int j = 0; j < 4; ++j)
                    acc[i][j] = __builtin_amdgcn_mfma_f32_16x16x32_bf16(
                        af[i], wf[j], acc[i][j], 0, 0, 0);
        }
    }

    #pragma unroll
    for (int i = 0; i < 4; ++i) {
        int mbase = m0 + hm + i * 16 + quad * 4;
        #pragma unroll
        for (int j = 0; j < 4; ++j) {
            int n = n0 + hn + j * 16 + lm;
            if (n < N) {
                float bv = bias ? bias[n] : 0.0f;
                #pragma unroll
                for (int rr = 0; rr < 4; ++rr)
                    C[(size_t)(mbase + rr) * N + n] = acc[i][j][rr] + bv;
            }
        }
    }
}

__global__ __launch_bounds__(256) void gemm_bf16_tn(
    const __hip_bfloat16* __restrict__ A, int lda,
    const __hip_bfloat16* __restrict__ W, int ldw,
    const float* __restrict__ bias, float* __restrict__ C,
    int M, int N, int K)
{
    gemm_body(A, lda, W, ldw, bias, C, M, N, K, blockIdx.x, blockIdx.y);
}

// split-K x2: blockIdx.z selects K-half; writes fp32 partials, no bias.
__global__ __launch_bounds__(256) void gemm_bf16_sk2(
    const __hip_bfloat16* __restrict__ A, int lda,
    const __hip_bfloat16* __restrict__ W, int ldw,
    float* __restrict__ Cpart, int M, int N, int Ksub)
{
    int z = blockIdx.z;
    gemm_body(A + (size_t)z * Ksub, lda, W + (size_t)z * Ksub, ldw, nullptr,
              Cpart + (size_t)z * M * N, M, N, Ksub, blockIdx.x, blockIdx.y);
}

// ===========================================================================
// Cast / split kernels.  x3 split: A3=[A_hi|A_lo|A_hi], W3=[W_hi|W_hi|W_lo]
// -> plain bf16 GEMM over 3K = A_hi*W_hi + A_lo*W_hi + A_hi*W_lo.
// ===========================================================================
__global__ __launch_bounds__(256) void split3_a_kernel(
    const float* __restrict__ in, int ldin,
    __hip_bfloat16* __restrict__ out, int ldo, int coff, int M, int K)
{
    int i = blockIdx.x * 256 + threadIdx.x;
    if (i >= M * K) return;
    int m = i / K, k = i - m * K;
    float v = in[(size_t)m * ldin + k];
    __hip_bfloat16 hi = __float2bfloat16(v);
    float lo = v - __bfloat162float(hi);
    __hip_bfloat16* row = out + (size_t)m * ldo + coff;
    row[k] = hi;
    row[K + k] = __float2bfloat16(lo);
    row[2 * K + k] = hi;
}

__global__ __launch_bounds__(256) void split3_w_kernel(
    const float* __restrict__ in, int ldin,
    __hip_bfloat16* __restrict__ out, int ldo, int coff, int M, int K)
{
    int i = blockIdx.x * 256 + threadIdx.x;
    if (i >= M * K) return;
    int m = i / K, k = i - m * K;
    float v = in[(size_t)m * ldin + k];
    __hip_bfloat16 hi = __float2bfloat16(v);
    float lo = v - __bfloat162float(hi);
    __hip_bfloat16* row = out + (size_t)m * ldo + coff;
    row[k] = hi;
    row[K + k] = hi;
    row[2 * K + k] = __float2bfloat16(lo);
}

__global__ __launch_bounds__(256) void cast2d_kernel(
    const float* __restrict__ in, int ldin,
    __hip_bfloat16* __restrict__ out, int ldo, int coff, int M, int K)
{
    int i = blockIdx.x * 256 + threadIdx.x;
    if (i >= M * K) return;
    int m = i / K, k = i - m * K;
    out[(size_t)m * ldo + coff + k] = __float2bfloat16(in[(size_t)m * ldin + k]);
}

// start-token gather with x3 split (stride 0 = broadcast scalar idx)
__global__ __launch_bounds__(256) void gather_split3_kernel(
    const float* __restrict__ emb, int E, const int* __restrict__ idx,
    int stride, __hip_bfloat16* __restrict__ out, int ldo, int Brows)
{
    int i = blockIdx.x * 256 + threadIdx.x;
    if (i >= Brows * E) return;
    int b = i / E, k = i - b * E;
    float v = emb[(size_t)idx[b * stride] * E + k];
    __hip_bfloat16 hi = __float2bfloat16(v);
    float lo = v - __bfloat162float(hi);
    __hip_bfloat16* row = out + (size_t)b * ldo;
    row[k] = hi;
    row[E + k] = __float2bfloat16(lo);
    row[2 * E + k] = hi;
}

__global__ __launch_bounds__(256) void gather_cast_kernel(
    const float* __restrict__ emb, int E, const int* __restrict__ idx,
    __hip_bfloat16* __restrict__ out, int ldo, int coff, int Brows)
{
    int i = blockIdx.x * 256 + threadIdx.x;
    if (i >= Brows * E) return;
    int b = i / E, k = i - b * E;
    out[(size_t)b * ldo + coff + k] =
        __float2bfloat16(emb[(size_t)idx[b] * E + k]);
}

__global__ __launch_bounds__(256) void add_vec_kernel(
    const float* __restrict__ a, const float* __restrict__ b,
    float* __restrict__ o, int n)
{
    int i = blockIdx.x * 256 + threadIdx.x;
    if (i < n) o[i] = a[i] + b[i];
}

// ===========================================================================
// Sender LSTM pointwise, fused with split-K combine + h split3 write.
// gates = gp0 + gp1 + bias (chunks i,f,g,o); writes h fp32 and split3(h) into
// xh3 cols [1536, 4608).
// ===========================================================================
__global__ __launch_bounds__(256) void lstm_fused_s(
    const float* __restrict__ gp0, const float* __restrict__ gp1,
    const float* __restrict__ bias, float* __restrict__ h,
    float* __restrict__ c, __hip_bfloat16* __restrict__ xh3)
{
    int i = blockIdx.x * 256 + threadIdx.x;
    if (i >= Bc * Hc) return;
    int b = i >> 10, j = i & (Hc - 1);
    size_t g0 = (size_t)b * G4c + j;
    float gi = gp0[g0]          + gp1[g0]          + bias[j];
    float gf = gp0[g0 + Hc]     + gp1[g0 + Hc]     + bias[Hc + j];
    float gg = gp0[g0 + 2 * Hc] + gp1[g0 + 2 * Hc] + bias[2 * Hc + j];
    float go = gp0[g0 + 3 * Hc] + gp1[g0 + 3 * Hc] + bias[3 * Hc + j];
    float si = 1.0f / (1.0f + expf(-gi));
    float sf = 1.0f / (1.0f + expf(-gf));
    float so = 1.0f / (1.0f + expf(-go));
    float cn = sf * c[i] + si * tanhf(gg);
    c[i] = cn;
    float hv = so * tanhf(cn);
    h[i] = hv;
    __hip_bfloat16 hi2 = __float2bfloat16(hv);
    float lo = hv - __bfloat162float(hi2);
    __hip_bfloat16* row = xh3 + (size_t)b * 4608 + 1536;
    row[j] = hi2;
    row[Hc + j] = __float2bfloat16(lo);
    row[2 * Hc + j] = hi2;
}

// h0 combine: h = p0 + p1 + bias; also split3 into xh3 h-region.
__global__ __launch_bounds__(256) void combine_h0_kernel(
    const float* __restrict__ p0, const float* __restrict__ p1,
    const float* __restrict__ bias, float* __restrict__ h,
    __hip_bfloat16* __restrict__ xh3)
{
    int i = blockIdx.x * 256 + threadIdx.x;
    if (i >= Bc * Hc) return;
    int b = i >> 10, j = i & (Hc - 1);
    float v = p0[i] + p1[i] + bias[j];
    h[i] = v;
    __hip_bfloat16 hi2 = __float2bfloat16(v);
    float lo = v - __bfloat162float(hi2);
    __hip_bfloat16* row = xh3 + (size_t)b * 4608 + 1536;
    row[j] = hi2;
    row[Hc + j] = __float2bfloat16(lo);
    row[2 * Hc + j] = hi2;
}

// ===========================================================================
// Receiver LSTM pointwise fused: split-K combine + h->bf16 into xh_r + gather
// of next token embedding into xh_r x-region.
// ===========================================================================
__global__ __launch_bounds__(256) void lstm_fused_r(
    const float* __restrict__ gp0, const float* __restrict__ gp1,
    const float* __restrict__ bias, float* __restrict__ h,
    float* __restrict__ c, __hip_bfloat16* __restrict__ xh_r,
    const float* __restrict__ emb, const int* __restrict__ msg_next)
{
    int i = blockIdx.x * 256 + threadIdx.x;
    if (i >= Bc * Hc) return;
    int b = i >> 10, j = i & (Hc - 1);
    size_t g0 = (size_t)b * G4c + j;
    float gi = gp0[g0]          + gp1[g0]          + bias[j];
    float gf = gp0[g0 + Hc]     + gp1[g0 + Hc]     + bias[Hc + j];
    float gg = gp0[g0 + 2 * Hc] + gp1[g0 + 2 * Hc] + bias[2 * Hc + j];
    float go = gp0[g0 + 3 * Hc] + gp1[g0 + 3 * Hc] + bias[3 * Hc + j];
    float si = 1.0f / (1.0f + expf(-gi));
    float sf = 1.0f / (1.0f + expf(-gf));
    float so = 1.0f / (1.0f + expf(-go));
    float cn = sf * c[i] + si * tanhf(gg);
    c[i] = cn;
    float hv = so * tanhf(cn);
    h[i] = hv;
    xh_r[(size_t)b * 1536 + Ec + j] = __float2bfloat16(hv);
    if (msg_next && j < Ec) {
        int tok = msg_next[b];
        xh_r[(size_t)b * 1536 + j] =
            __float2bfloat16(emb[(size_t)tok * Ec + j]);
    }
}

// ===========================================================================
// Fused argmax: approx (bf16-GEMM) logits -> candidate set (within delta of
// max) -> exact fp32 rescore (h fp32 x Wp fp32) -> token + optional logp +
// next-token embedding gather (split3 into xh3).
// One block per batch row, 256 threads.
// ===========================================================================
__global__ __launch_bounds__(256) void argmax_rescore_kernel(
    const float* __restrict__ logits, const float* __restrict__ h,
    const float* __restrict__ Wp, const float* __restrict__ bp,
    const float* __restrict__ emb, int* __restrict__ msg_t,
    float* __restrict__ logp, __hip_bfloat16* __restrict__ xh3,
    int want_logp)
{
    const int b = blockIdx.x;
    const int tid = threadIdx.x;
    const float* row = logits + (size_t)b * Vc;

    __shared__ float sv[256];
    __shared__ int   cand[64];
    __shared__ int   cnt;
    __shared__ float bestv;
    __shared__ int   bestj;

    // pass 1: approx max
    float lm = -__builtin_inff();
    for (int j = tid; j < Vc; j += 256) lm = fmaxf(lm, row[j]);
    sv[tid] = lm;
    __syncthreads();
    for (int s = 128; s > 0; s >>= 1) {
        if (tid < s) sv[tid] = fmaxf(sv[tid], sv[tid + s]);
        __syncthreads();
    }
    float m = sv[0];
    __syncthreads();

    // pass 2: candidates + (optional) sumexp
    if (tid == 0) { cnt = 0; bestv = -__builtin_inff(); bestj = 0x7fffffff; }
    __syncthreads();
    float delta = 1e-2f + 3e-3f * fabsf(m);
    float s_exp = 0.0f;
    for (int j = tid; j < Vc; j += 256) {
        float v = row[j];
        if (want_logp) s_exp += expf(v - m);
        if (v > m - delta) {
            int k = atomicAdd(&cnt, 1);
            if (k < 64) cand[k] = j;
        }
    }
    __syncthreads();
    int nc = cnt < 64 ? cnt : 64;
    sv[tid] = s_exp;
    __syncthreads();
    for (int s = 128; s > 0; s >>= 1) {
        if (tid < s) sv[tid] += sv[tid + s];
        __syncthreads();
    }
    float se = sv[0];
    __syncthreads();

    // rescore candidates with exact fp32 dot
    const float* hrow = h + (size_t)b * Hc;
    for (int cix = 0; cix < nc; ++cix) {
        int j = cand[cix];
        const float* wrow = Wp + (size_t)j * Hc;
        float part = 0.0f;
        for (int k = tid; k < Hc; k += 256) part = fmaf(hrow[k], wrow[k], part);
        __syncthreads();
        sv[tid] = part;
        __syncthreads();
        for (int s = 128; s > 0; s >>= 1) {
            if (tid < s) sv[tid] += sv[tid + s];
            __syncthreads();
        }
        if (tid == 0) {
            float val = sv[0] + bp[j];
            if (val > bestv || (val == bestv && j < bestj)) {
                bestv = val; bestj = j;
            }
        }
        __syncthreads();
    }

    if (tid == 0) {
        msg_t[b] = bestj;
        if (want_logp) logp[b] = bestv - (m + logf(se));
    }
    __syncthreads();

    // gather next-token embedding, split3, into xh3 x-region
    if (xh3) {
        int tok = bestj;
        __hip_bfloat16* orow = xh3 + (size_t)b * 4608;
        for (int k = tid; k < Ec; k += 256) {
            float v = emb[(size_t)tok * Ec + k];
            __hip_bfloat16 hi2 = __float2bfloat16(v);
            float lo = v - __bfloat162float(hi2);
            orow[k] = hi2;
            orow[Ec + k] = __float2bfloat16(lo);
            orow[2 * Ec + k] = hi2;
        }
    }
}

// ===========================================================================
// Hinge loss partial reduction; S layout [4][B][B], fast axis j weights logp
// ===========================================================================
__global__ __launch_bounds__(256) void hinge_kernel(
    const float* __restrict__ S, const float* __restrict__ logp,
    float* __restrict__ partials, int Bn)
{
    int tid = threadIdx.x;
    int n = Bn * Bn;
    float acc = 0.0f;
    for (int idx = blockIdx.x * 256 + tid; idx < n; idx += gridDim.x * 256) {
        int j = idx & (Bn - 1);
        float s0 = S[idx];
        float l = fmaxf(0.0f, 1.0f - s0 + S[n + idx])
                + fmaxf(0.0f, 1.0f - s0 + S[2 * n + idx])
                + fmaxf(0.0f, 1.0f - s0 + S[3 * n + idx]);
        acc += l * logp[j];
    }
    __shared__ float sv[256];
    sv[tid] = acc;
    __syncthreads();
    for (int s = 128; s > 0; s >>= 1) {
        if (tid < s) sv[tid] += sv[tid + s];
        __syncthreads();
    }
    if (tid == 0) partials[blockIdx.x] = sv[0];
}

__global__ __launch_bounds__(256) void final_reduce_kernel(
    const float* __restrict__ partials, int np, float* __restrict__ out,
    float scale)
{
    int tid = threadIdx.x;
    float acc = 0.0f;
    for (int i = tid; i < np; i += 256) acc += partials[i];
    __shared__ float sv[256];
    sv[tid] = acc;
    __syncthreads();
    for (int s = 128; s > 0; s >>= 1) {
        if (tid < s) sv[tid] += sv[tid + s];
        __syncthreads();
    }
    if (tid == 0) out[0] = sv[0] * scale;
}

// ===========================================================================
extern "C" void kernel_launch(void* const* d_in, const int* in_sizes, int n_in,
                              void* d_out, int out_size, void* d_ws, size_t ws_size,
                              hipStream_t stream)
{
    (void)in_sizes; (void)n_in; (void)out_size; (void)ws_size;

    const float* target  = (const float*)d_in[0];
    const float* distr   = (const float*)d_in[1];
    const int*   start_t = (const int*)d_in[2];
    const float* W_aff = (const float*)d_in[4];
    const float* b_aff = (const float*)d_in[5];
    const float* emb_s = (const float*)d_in[6];
    const float* Wih_s = (const float*)d_in[7];
    const float* Whh_s = (const float*)d_in[8];
    const float* bih_s = (const float*)d_in[9];
    const float* bhh_s = (const float*)d_in[10];
    const float* Wp    = (const float*)d_in[11];
    const float* bp    = (const float*)d_in[12];
    const float* emb_r = (const float*)d_in[13];
    const float* Wih_r = (const float*)d_in[14];
    const float* Whh_r = (const float*)d_in[15];
    const float* bih_r = (const float*)d_in[16];
    const float* bhh_r = (const float*)d_in[17];
    const float* W_out = (const float*)d_in[18];
    const float* b_out = (const float*)d_in[19];

    dim3 blk(256);

    // ---------------- workspace layout ----------------
    char* b0 = (char*)d_ws;
    size_t off = 0;
    auto take = [&](size_t bytes) -> char* {
        char* p = b0 + off;
        off += (bytes + 511) & ~(size_t)511;
        return p;
    };
    const size_t MB = 1024 * 1024;
    __hip_bfloat16* WihWhh3 = (__hip_bfloat16*)take((size_t)G4c * 4608 * 2);
    __hip_bfloat16* Wp_b    = (__hip_bfloat16*)take((size_t)Vc * Hc * 2);
    __hip_bfloat16* WihWhh_r= (__hip_bfloat16*)take((size_t)G4c * 1536 * 2);
    __hip_bfloat16* W_out_b = (__hip_bfloat16*)take((size_t)NIFc * Hc * 2);
    __hip_bfloat16* xh3     = (__hip_bfloat16*)take((size_t)Bc * 4608 * 2);
    __hip_bfloat16* xh_r    = (__hip_bfloat16*)take((size_t)Bc * 1536 * 2);
    float* gates_p = (float*)take((size_t)2 * Bc * G4c * 4);  // split-K partials
    float* h_s    = (float*)take((size_t)Bc * Hc * 4);
    float* c_s    = (float*)take((size_t)Bc * Hc * 4);
    float* hr     = (float*)take((size_t)Bc * Hc * 4);
    float* cr     = (float*)take((size_t)Bc * Hc * 4);
    float* logp   = (float*)take(Bc * 4);
    int*   msg    = (int*)take((size_t)Lc * Bc * 4);
    float* parts  = (float*)take(1024 * 4);
    float* bias_s = (float*)take(G4c * 4);
    float* bias_r = (float*)take(G4c * 4);
    char*  U      = take(48 * MB);

    // U sub-layout (phased reuse)
    __hip_bfloat16* target3 = (__hip_bfloat16*)U;                 // phase 1
    __hip_bfloat16* W_aff3  = (__hip_bfloat16*)(U + 13 * MB);     // phase 1
    float*          logits  = (float*)U;                          // phase 2 (40MB)
    __hip_bfloat16* A4b     = (__hip_bfloat16*)U;                 // phase 3
    float*          r_f     = (float*)(U + 17 * MB);              // phase 3
    __hip_bfloat16* r_b     = (__hip_bfloat16*)(U + 26 * MB);     // phase 3
    float*          S       = (float*)(U + 31 * MB);              // phase 3

    // ---- weight prep (per launch; one-time cost) ----
    split3_w_kernel<<<(G4c * Ec + 255) / 256, blk, 0, stream>>>(
        Wih_s, Ec, WihWhh3, 4608, 0, G4c, Ec);
    split3_w_kernel<<<(G4c * Hc + 255) / 256, blk, 0, stream>>>(
        Whh_s, Hc, WihWhh3, 4608, 1536, G4c, Hc);
    cast2d_kernel<<<(Vc * Hc + 255) / 256, blk, 0, stream>>>(
        Wp, Hc, Wp_b, Hc, 0, Vc, Hc);
    split3_a_kernel<<<(Bc * NIFc + 255) / 256, blk, 0, stream>>>(
        target, NIFc, target3, 6144, 0, Bc, NIFc);
    split3_w_kernel<<<(Hc * NIFc + 255) / 256, blk, 0, stream>>>(
        W_aff, NIFc, W_aff3, 6144, 0, Hc, NIFc);
    cast2d_kernel<<<(G4c * Ec + 255) / 256, blk, 0, stream>>>(
        Wih_r, Ec, WihWhh_r, 1536, 0, G4c, Ec);
    cast2d_kernel<<<(G4c * Hc + 255) / 256, blk, 0, stream>>>(
        Whh_r, Hc, WihWhh_r, 1536, Ec, G4c, Hc);
    cast2d_kernel<<<(NIFc * Hc + 255) / 256, blk, 0, stream>>>(
        W_out, Hc, W_out_b, Hc, 0, NIFc, Hc);
    add_vec_kernel<<<(G4c + 255) / 256, blk, 0, stream>>>(bih_s, bhh_s,
                                                          bias_s, G4c);
    add_vec_kernel<<<(G4c + 255) / 256, blk, 0, stream>>>(bih_r, bhh_r,
                                                          bias_r, G4c);

    // ---- sender init: h0 = target @ W_aff^T + b_aff (x3, split-K x2) ----
    gemm_bf16_sk2<<<dim3(Hc / GBN, Bc / GBM, 2), blk, 0, stream>>>(
        target3, 6144, W_aff3, 6144, gates_p, Bc, Hc, 3072);
    combine_h0_kernel<<<(Bc * Hc + 255) / 256, blk, 0, stream>>>(
        gates_p, gates_p + (size_t)Bc * Hc, b_aff, h_s, xh3);
    hipMemsetAsync(c_s, 0, (size_t)Bc * Hc * 4, stream);
    gather_split3_kernel<<<(Bc * Ec + 255) / 256, blk, 0, stream>>>(
        emb_s, Ec, start_t, 0, xh3, 4608, Bc);

    // ---- sender greedy decode ----
    for (int t = 0; t < Lc; ++t) {
        // gates partials: [wv|h] @ [Wih|Whh]^T (x3, K=4608, split-K x2)
        gemm_bf16_sk2<<<dim3(G4c / GBN, Bc / GBM, 2), blk, 0, stream>>>(
            xh3, 4608, WihWhh3, 4608, gates_p, Bc, G4c, 2304);
        lstm_fused_s<<<(Bc * Hc + 255) / 256, blk, 0, stream>>>(
            gates_p, gates_p + (size_t)Bc * G4c, bias_s, h_s, c_s, xh3);
        // approx logits = h_hi @ Wp_b^T + bp (plain bf16, K=1024)
        gemm_bf16_tn<<<dim3((Vc + GBN - 1) / GBN, Bc / GBM), blk, 0, stream>>>(
            xh3 + 1536, 4608, Wp_b, Hc, bp, logits, Bc, Vc, Hc);
        // exact-rescored argmax + logp + next-token gather
        argmax_rescore_kernel<<<Bc, blk, 0, stream>>>(
            logits, h_s, Wp, bp, emb_s, msg + t * Bc, logp,
            (t < Lc - 1) ? xh3 : nullptr, (t == Lc - 1) ? 1 : 0);
    }

    // ---- receiver ----
    hipMemsetAsync(hr, 0, (size_t)Bc * Hc * 4, stream);
    hipMemsetAsync(cr, 0, (size_t)Bc * Hc * 4, stream);
    hipMemsetAsync(xh_r, 0, (size_t)Bc * 1536 * 2, stream);
    gather_cast_kernel<<<(Bc * Ec + 255) / 256, blk, 0, stream>>>(
        emb_r, Ec, msg, xh_r, 1536, 0, Bc);
    for (int t = 0; t < Lc; ++t) {
        gemm_bf16_sk2<<<dim3(G4c / GBN, Bc / GBM, 2), blk, 0, stream>>>(
            xh_r, 1536, WihWhh_r, 1536, gates_p, Bc, G4c, 768);
        lstm_fused_r<<<(Bc * Hc + 255) / 256, blk, 0, stream>>>(
            gates_p, gates_p + (size_t)Bc * G4c, bias_r, hr, cr, xh_r,
            emb_r, (t < Lc - 1) ? (msg + (t + 1) * Bc) : nullptr);
    }

    // ---- r = hr @ W_out^T + b_out ----
    gemm_bf16_tn<<<dim3(NIFc / GBN, Bc / GBM), blk, 0, stream>>>(
        xh_r + Ec, 1536, W_out_b, Hc, b_out, r_f, Bc, NIFc, Hc);

    // ---- similarities: [target; distractors] @ r^T in ONE GEMM ----
    cast2d_kernel<<<(Bc * NIFc + 255) / 256, blk, 0, stream>>>(
        target, NIFc, A4b, NIFc, 0, Bc, NIFc);
    cast2d_kernel<<<(NDc * Bc * NIFc + 255) / 256, blk, 0, stream>>>(
        distr, NIFc, A4b + (size_t)Bc * NIFc, NIFc, 0, NDc * Bc, NIFc);
    cast2d_kernel<<<(Bc * NIFc + 255) / 256, blk, 0, stream>>>(
        r_f, NIFc, r_b, NIFc, 0, Bc, NIFc);
    gemm_bf16_tn<<<dim3(Bc / GBN, 4 * Bc / GBM), blk, 0, stream>>>(
        A4b, NIFc, r_b, NIFc, nullptr, S, 4 * Bc, Bc, NIFc);

    hinge_kernel<<<1024, blk, 0, stream>>>(S, logp, parts, Bc);
    final_reduce_kernel<<<1, blk, 0, stream>>>(
        parts, 1024, (float*)d_out, -1.0f / ((float)Bc * (float)Bc));
}

// Round 4
// 7690.443 us; speedup vs baseline: 4.7269x; 1.0627x over previous
//
#include <hip/hip_runtime.h>
#include <hip/hip_bf16.h>
#include <cstdint>
#include <cstddef>

// Problem constants (fixed by setup_inputs in the reference)
#define Bc   1024
#define NIFc 2048
#define Vc   10000
#define Ec   512
#define Hc   1024
#define Lc   32
#define NDc  3
#define G4c  4096   // 4*H
#define NTv  79     // ceil(V/128) logits tiles
#define TMLD 80     // tilemax row stride

typedef __attribute__((ext_vector_type(4))) float f32x4;
typedef __attribute__((ext_vector_type(8))) short s16x8;
typedef __attribute__((ext_vector_type(4))) short s16x4;

// ===========================================================================
// bf16 MFMA GEMM body:  C[M,N] = A[M,K] @ W[N,K]^T (+ bias[N])
// 128x128 tile, BK=64, 256 thr (4 waves 2x2), 4x4 MFMA 16x16x32/wave.
// global_load_lds w=16 staging, XOR-swizzled LDS chunks (2-way alias = free).
// Optional epilogue: per-row max over this block's 128 cols -> tile_max.
// ===========================================================================
#define GBM 128
#define GBN 128
#define GBK 64

__device__ __forceinline__ void gld_lds16(void* lds, const void* g) {
    __builtin_amdgcn_global_load_lds(
        (const __attribute__((address_space(1))) unsigned int*)g,
        (__attribute__((address_space(3))) unsigned int*)lds,
        16, 0, 0);
}

__device__ __forceinline__ void gemm_body(
    const __hip_bfloat16* __restrict__ A, int lda,
    const __hip_bfloat16* __restrict__ W, int ldw,
    const float* __restrict__ bias, float* __restrict__ C,
    int M, int N, int K, int bx, int by,
    float* __restrict__ tile_max, int tmld)
{
    __shared__ __align__(16) __hip_bfloat16 As[GBM * GBK];
    __shared__ __align__(16) __hip_bfloat16 Ws[GBN * GBK];
    __shared__ float smax[GBM];

    const int tid  = threadIdx.x;
    const int lane = tid & 63;
    const int wave = tid >> 6;
    const int m0 = by * GBM;
    const int n0 = bx * GBN;

    const __hip_bfloat16* ag[4];
    const __hip_bfloat16* wg[4];
    #pragma unroll
    for (int r = 0; r < 4; ++r) {
        int p = r * 256 + tid;
        int m = p >> 3;
        int q = (p & 7) ^ (m & 7);
        ag[r] = A + (size_t)(m0 + m) * lda + q * 8;
        int wn = n0 + m; if (wn >= N) wn = N - 1;
        wg[r] = W + (size_t)wn * ldw + q * 8;
    }

    f32x4 acc[4][4];
    #pragma unroll
    for (int i = 0; i < 4; ++i)
        #pragma unroll
        for (int j = 0; j < 4; ++j)
            acc[i][j] = (f32x4)(0.0f);

    const int hm = (wave & 1) << 6;
    const int hn = (wave >> 1) << 6;
    const int lm = lane & 15;
    const int quad = lane >> 4;

    const int nk = K >> 6;
    for (int kt = 0; kt < nk; ++kt) {
        __syncthreads();
        #pragma unroll
        for (int r = 0; r < 4; ++r) {
            int ldsbase = (r * 256 + wave * 64) * 8;
            gld_lds16(As + ldsbase, ag[r]);
            gld_lds16(Ws + ldsbase, wg[r]);
            ag[r] += GBK;
            wg[r] += GBK;
        }
        __syncthreads();
        #pragma unroll
        for (int c = 0; c < 2; ++c) {
            s16x8 af[4], wf[4];
            int q = c * 4 + quad;
            #pragma unroll
            for (int i = 0; i < 4; ++i) {
                int m = hm + i * 16 + lm;
                af[i] = *(const s16x8*)(As + ((m << 3) + (q ^ (m & 7))) * 8);
                int n = hn + i * 16 + lm;
                wf[i] = *(const s16x8*)(Ws + ((n << 3) + (q ^ (n & 7))) * 8);
            }
            #pragma unroll
            for (int i = 0; i < 4; ++i)
                #pragma unroll
                for (int j = 0; j < 4; ++j)
                    acc[i][j] = __builtin_amdgcn_mfma_f32_16x16x32_bf16(
                        af[i], wf[j], acc[i][j], 0, 0, 0);
        }
    }

    // epilogue: C/D layout col=lane&15, row=quad*4+reg
    float rowmax[4][4];
    #pragma unroll
    for (int i = 0; i < 4; ++i)
        #pragma unroll
        for (int rr = 0; rr < 4; ++rr)
            rowmax[i][rr] = -__builtin_inff();

    #pragma unroll
    for (int i = 0; i < 4; ++i) {
        int mbase = m0 + hm + i * 16 + quad * 4;
        #pragma unroll
        for (int j = 0; j < 4; ++j) {
            int n = n0 + hn + j * 16 + lm;
            if (n < N) {
                float bv = bias ? bias[n] : 0.0f;
                #pragma unroll
                for (int rr = 0; rr < 4; ++rr) {
                    float v = acc[i][j][rr] + bv;
                    C[(size_t)(mbase + rr) * N + n] = v;
                    rowmax[i][rr] = fmaxf(rowmax[i][rr], v);
                }
            }
        }
    }

    if (tile_max) {
        // reduce each (i,rr) row-max across the quad's 16 lanes
        #pragma unroll
        for (int i = 0; i < 4; ++i)
            #pragma unroll
            for (int rr = 0; rr < 4; ++rr) {
                float v = rowmax[i][rr];
                v = fmaxf(v, __shfl_xor(v, 1));
                v = fmaxf(v, __shfl_xor(v, 2));
                v = fmaxf(v, __shfl_xor(v, 4));
                v = fmaxf(v, __shfl_xor(v, 8));
                rowmax[i][rr] = v;
            }
        __syncthreads();   // done with As/Ws; smax phase begins
        if (hn == 0 && lm == 0) {
            #pragma unroll
            for (int i = 0; i < 4; ++i)
                #pragma unroll
                for (int rr = 0; rr < 4; ++rr)
                    smax[hm + i * 16 + quad * 4 + rr] = rowmax[i][rr];
        }
        __syncthreads();
        if (hn == 64 && lm == 0) {
            #pragma unroll
            for (int i = 0; i < 4; ++i)
                #pragma unroll
                for (int rr = 0; rr < 4; ++rr) {
                    int r = hm + i * 16 + quad * 4 + rr;
                    smax[r] = fmaxf(smax[r], rowmax[i][rr]);
                }
        }
        __syncthreads();
        if (tid < GBM)
            tile_max[(size_t)(m0 + tid) * tmld + bx] = smax[tid];
    }
}

__global__ __launch_bounds__(256) void gemm_bf16_tn(
    const __hip_bfloat16* __restrict__ A, int lda,
    const __hip_bfloat16* __restrict__ W, int ldw,
    const float* __restrict__ bias, float* __restrict__ C,
    int M, int N, int K, float* __restrict__ tile_max, int tmld)
{
    gemm_body(A, lda, W, ldw, bias, C, M, N, K, blockIdx.x, blockIdx.y,
              tile_max, tmld);
}

// split-K x2: blockIdx.z selects K-half; fp32 partials, no bias.
__global__ __launch_bounds__(256) void gemm_bf16_sk2(
    const __hip_bfloat16* __restrict__ A, int lda,
    const __hip_bfloat16* __restrict__ W, int ldw,
    float* __restrict__ Cpart, int M, int N, int Ksub)
{
    int z = blockIdx.z;
    gemm_body(A + (size_t)z * Ksub, lda, W + (size_t)z * Ksub, ldw, nullptr,
              Cpart + (size_t)z * M * N, M, N, Ksub, blockIdx.x, blockIdx.y,
              nullptr, 0);
}

// ===========================================================================
// Cast / split kernels.  x3 split: A3=[A_hi|A_lo|A_hi], W3=[W_hi|W_hi|W_lo]
// ===========================================================================
__global__ __launch_bounds__(256) void split3_a_kernel(
    const float* __restrict__ in, int ldin,
    __hip_bfloat16* __restrict__ out, int ldo, int coff, int M, int K)
{
    int i = blockIdx.x * 256 + threadIdx.x;
    if (i >= M * K) return;
    int m = i / K, k = i - m * K;
    float v = in[(size_t)m * ldin + k];
    __hip_bfloat16 hi = __float2bfloat16(v);
    float lo = v - __bfloat162float(hi);
    __hip_bfloat16* row = out + (size_t)m * ldo + coff;
    row[k] = hi;
    row[K + k] = __float2bfloat16(lo);
    row[2 * K + k] = hi;
}

__global__ __launch_bounds__(256) void split3_w_kernel(
    const float* __restrict__ in, int ldin,
    __hip_bfloat16* __restrict__ out, int ldo, int coff, int M, int K)
{
    int i = blockIdx.x * 256 + threadIdx.x;
    if (i >= M * K) return;
    int m = i / K, k = i - m * K;
    float v = in[(size_t)m * ldin + k];
    __hip_bfloat16 hi = __float2bfloat16(v);
    float lo = v - __bfloat162float(hi);
    __hip_bfloat16* row = out + (size_t)m * ldo + coff;
    row[k] = hi;
    row[K + k] = hi;
    row[2 * K + k] = __float2bfloat16(lo);
}

__global__ __launch_bounds__(256) void cast2d_kernel(
    const float* __restrict__ in, int ldin,
    __hip_bfloat16* __restrict__ out, int ldo, int coff, int M, int K)
{
    int i = blockIdx.x * 256 + threadIdx.x;
    if (i >= M * K) return;
    int m = i / K, k = i - m * K;
    out[(size_t)m * ldo + coff + k] = __float2bfloat16(in[(size_t)m * ldin + k]);
}

__global__ __launch_bounds__(256) void gather_split3_kernel(
    const float* __restrict__ emb, int E, const int* __restrict__ idx,
    int stride, __hip_bfloat16* __restrict__ out, int ldo, int Brows)
{
    int i = blockIdx.x * 256 + threadIdx.x;
    if (i >= Brows * E) return;
    int b = i / E, k = i - b * E;
    float v = emb[(size_t)idx[b * stride] * E + k];
    __hip_bfloat16 hi = __float2bfloat16(v);
    float lo = v - __bfloat162float(hi);
    __hip_bfloat16* row = out + (size_t)b * ldo;
    row[k] = hi;
    row[E + k] = __float2bfloat16(lo);
    row[2 * E + k] = hi;
}

__global__ __launch_bounds__(256) void gather_cast_kernel(
    const float* __restrict__ emb, int E, const int* __restrict__ idx,
    __hip_bfloat16* __restrict__ out, int ldo, int coff, int Brows)
{
    int i = blockIdx.x * 256 + threadIdx.x;
    if (i >= Brows * E) return;
    int b = i / E, k = i - b * E;
    out[(size_t)b * ldo + coff + k] =
        __float2bfloat16(emb[(size_t)idx[b] * E + k]);
}

__global__ __launch_bounds__(256) void add_vec_kernel(
    const float* __restrict__ a, const float* __restrict__ b,
    float* __restrict__ o, int n)
{
    int i = blockIdx.x * 256 + threadIdx.x;
    if (i < n) o[i] = a[i] + b[i];
}

// ===========================================================================
// Vectorized LSTM pointwise kernels (float4 loads, 8B bf16 stores)
// ===========================================================================
__device__ __forceinline__ short bf16bits(float x) {
    __hip_bfloat16 t = __float2bfloat16(x);
    return *reinterpret_cast<short*>(&t);
}

__global__ __launch_bounds__(256) void lstm_fused_s(
    const float* __restrict__ gp0, const float* __restrict__ gp1,
    const float* __restrict__ bias, float* __restrict__ h,
    float* __restrict__ c, __hip_bfloat16* __restrict__ xh3)
{
    int i = blockIdx.x * 256 + threadIdx.x;      // over Bc*Hc/4
    if (i >= Bc * Hc / 4) return;
    int b = i >> 8;
    int j = (i & 255) * 4;
    size_t g0 = (size_t)b * G4c + j;
    f32x4 gi = *(const f32x4*)(gp0 + g0) + *(const f32x4*)(gp1 + g0)
             + *(const f32x4*)(bias + j);
    f32x4 gf = *(const f32x4*)(gp0 + g0 + Hc) + *(const f32x4*)(gp1 + g0 + Hc)
             + *(const f32x4*)(bias + Hc + j);
    f32x4 gg = *(const f32x4*)(gp0 + g0 + 2 * Hc) + *(const f32x4*)(gp1 + g0 + 2 * Hc)
             + *(const f32x4*)(bias + 2 * Hc + j);
    f32x4 go = *(const f32x4*)(gp0 + g0 + 3 * Hc) + *(const f32x4*)(gp1 + g0 + 3 * Hc)
             + *(const f32x4*)(bias + 3 * Hc + j);
    size_t hix = (size_t)b * Hc + j;
    f32x4 cv = *(const f32x4*)(c + hix);
    f32x4 cn, hv;
    s16x4 hi4, lo4;
    #pragma unroll
    for (int k = 0; k < 4; ++k) {
        float si = 1.0f / (1.0f + expf(-gi[k]));
        float sf = 1.0f / (1.0f + expf(-gf[k]));
        float so = 1.0f / (1.0f + expf(-go[k]));
        float cc = sf * cv[k] + si * tanhf(gg[k]);
        cn[k] = cc;
        float hh = so * tanhf(cc);
        hv[k] = hh;
        hi4[k] = bf16bits(hh);
        lo4[k] = bf16bits(hh - __bfloat162float(__float2bfloat16(hh)));
    }
    *(f32x4*)(c + hix) = cn;
    *(f32x4*)(h + hix) = hv;
    __hip_bfloat16* row = xh3 + (size_t)b * 4608 + 1536;
    *(s16x4*)(row + j) = hi4;
    *(s16x4*)(row + Hc + j) = lo4;
    *(s16x4*)(row + 2 * Hc + j) = hi4;
}

__global__ __launch_bounds__(256) void combine_h0_kernel(
    const float* __restrict__ p0, const float* __restrict__ p1,
    const float* __restrict__ bias, float* __restrict__ h,
    __hip_bfloat16* __restrict__ xh3)
{
    int i = blockIdx.x * 256 + threadIdx.x;
    if (i >= Bc * Hc / 4) return;
    int b = i >> 8;
    int j = (i & 255) * 4;
    size_t ix = (size_t)b * Hc + j;
    f32x4 v = *(const f32x4*)(p0 + ix) + *(const f32x4*)(p1 + ix)
            + *(const f32x4*)(bias + j);
    *(f32x4*)(h + ix) = v;
    s16x4 hi4, lo4;
    #pragma unroll
    for (int k = 0; k < 4; ++k) {
        hi4[k] = bf16bits(v[k]);
        lo4[k] = bf16bits(v[k] - __bfloat162float(__float2bfloat16(v[k])));
    }
    __hip_bfloat16* row = xh3 + (size_t)b * 4608 + 1536;
    *(s16x4*)(row + j) = hi4;
    *(s16x4*)(row + Hc + j) = lo4;
    *(s16x4*)(row + 2 * Hc + j) = hi4;
}

__global__ __launch_bounds__(256) void lstm_fused_r(
    const float* __restrict__ gp0, const float* __restrict__ gp1,
    const float* __restrict__ bias, float* __restrict__ h,
    float* __restrict__ c, __hip_bfloat16* __restrict__ xh_r,
    const float* __restrict__ emb, const int* __restrict__ msg_next)
{
    int i = blockIdx.x * 256 + threadIdx.x;
    if (i >= Bc * Hc / 4) return;
    int b = i >> 8;
    int j = (i & 255) * 4;
    size_t g0 = (size_t)b * G4c + j;
    f32x4 gi = *(const f32x4*)(gp0 + g0) + *(const f32x4*)(gp1 + g0)
             + *(const f32x4*)(bias + j);
    f32x4 gf = *(const f32x4*)(gp0 + g0 + Hc) + *(const f32x4*)(gp1 + g0 + Hc)
             + *(const f32x4*)(bias + Hc + j);
    f32x4 gg = *(const f32x4*)(gp0 + g0 + 2 * Hc) + *(const f32x4*)(gp1 + g0 + 2 * Hc)
             + *(const f32x4*)(bias + 2 * Hc + j);
    f32x4 go = *(const f32x4*)(gp0 + g0 + 3 * Hc) + *(const f32x4*)(gp1 + g0 + 3 * Hc)
             + *(const f32x4*)(bias + 3 * Hc + j);
    size_t hix = (size_t)b * Hc + j;
    f32x4 cv = *(const f32x4*)(c + hix);
    f32x4 cn, hv;
    s16x4 hb4;
    #pragma unroll
    for (int k = 0; k < 4; ++k) {
        float si = 1.0f / (1.0f + expf(-gi[k]));
        float sf = 1.0f / (1.0f + expf(-gf[k]));
        float so = 1.0f / (1.0f + expf(-go[k]));
        float cc = sf * cv[k] + si * tanhf(gg[k]);
        cn[k] = cc;
        float hh = so * tanhf(cc);
        hv[k] = hh;
        hb4[k] = bf16bits(hh);
    }
    *(f32x4*)(c + hix) = cn;
    *(f32x4*)(h + hix) = hv;
    *(s16x4*)(xh_r + (size_t)b * 1536 + Ec + j) = hb4;
    if (msg_next && j < Ec) {
        int tok = msg_next[b];
        f32x4 e = *(const f32x4*)(emb + (size_t)tok * Ec + j);
        s16x4 eb;
        #pragma unroll
        for (int k = 0; k < 4; ++k) eb[k] = bf16bits(e[k]);
        *(s16x4*)(xh_r + (size_t)b * 1536 + j) = eb;
    }
}

// ===========================================================================
// Tile-max based argmax: read 79 tile maxima -> global approx max m ->
// scan only delta-qualifying tiles for candidates -> exact fp32 rescore ->
// token + optional logp (full-row float4 sumexp) + next-token split3 gather.
// One block per batch row.
// ===========================================================================
__global__ __launch_bounds__(256) void argmax_rescore_v2(
    const float* __restrict__ logits, const float* __restrict__ tmax,
    const float* __restrict__ h, const float* __restrict__ Wp,
    const float* __restrict__ bp, const float* __restrict__ emb,
    int* __restrict__ msg_t, float* __restrict__ logp,
    __hip_bfloat16* __restrict__ xh3, int want_logp)
{
    const int b = blockIdx.x;
    const int tid = threadIdx.x;
    const float* row = logits + (size_t)b * Vc;

    __shared__ float sv[256];
    __shared__ float stm[128];
    __shared__ int   qt[16];
    __shared__ int   nq;
    __shared__ int   cand[64];
    __shared__ int   cnt;
    __shared__ float bestv;
    __shared__ int   bestj;

    if (tid < 128)
        stm[tid] = (tid < NTv) ? tmax[(size_t)b * TMLD + tid]
                               : -__builtin_inff();
    if (tid == 0) { nq = 0; cnt = 0; bestv = -__builtin_inff(); bestj = 0x7fffffff; }
    __syncthreads();

    // global approx max over tile maxima
    float m_ = (tid < 128) ? stm[tid] : -__builtin_inff();
    sv[tid] = m_;
    __syncthreads();
    for (int s = 128; s > 0; s >>= 1) {
        if (tid < s) sv[tid] = fmaxf(sv[tid], sv[tid + s]);
        __syncthreads();
    }
    float m = sv[0];
    __syncthreads();
    float delta = 1e-2f + 3e-3f * fabsf(m);

    // qualifying tiles
    if (tid < NTv && stm[tid] > m - delta) {
        int k = atomicAdd(&nq, 1);
        if (k < 16) qt[k] = tid;
    }
    __syncthreads();
    int nqt = nq < 16 ? nq : 16;

    // candidate collection (scan only qualifying tiles)
    for (int qi = 0; qi < nqt; ++qi) {
        int j = qt[qi] * 128 + tid;
        if (tid < 128 && j < Vc) {
            float v = row[j];
            if (v > m - delta) {
                int k = atomicAdd(&cnt, 1);
                if (k < 64) cand[k] = j;
            }
        }
    }
    __syncthreads();
    int nc = cnt < 64 ? cnt : 64;

    // exact fp32 rescore
    const float* hrow = h + (size_t)b * Hc;
    for (int cix = 0; cix < nc; ++cix) {
        int j = cand[cix];
        const float* wrow = Wp + (size_t)j * Hc;
        float part = 0.0f;
        for (int k = tid; k < Hc; k += 256) part = fmaf(hrow[k], wrow[k], part);
        __syncthreads();
        sv[tid] = part;
        __syncthreads();
        for (int s = 128; s > 0; s >>= 1) {
            if (tid < s) sv[tid] += sv[tid + s];
            __syncthreads();
        }
        if (tid == 0) {
            float val = sv[0] + bp[j];
            if (val > bestv || (val == bestv && j < bestj)) {
                bestv = val; bestj = j;
            }
        }
        __syncthreads();
    }

    if (tid == 0) msg_t[b] = bestj;

    if (want_logp) {
        float s = 0.0f;
        const f32x4* row4 = (const f32x4*)row;       // Vc % 4 == 0
        for (int j = tid; j < Vc / 4; j += 256) {
            f32x4 v = row4[j];
            s += expf(v.x - m) + expf(v.y - m) + expf(v.z - m) + expf(v.w - m);
        }
        sv[tid] = s;
        __syncthreads();
        for (int st = 128; st > 0; st >>= 1) {
            if (tid < st) sv[tid] += sv[tid + st];
            __syncthreads();
        }
        if (tid == 0) logp[b] = bestv - (m + logf(sv[0]));
    }
    __syncthreads();

    // next-token embedding gather, split3, into xh3 x-region
    if (xh3) {
        int tok = bestj;
        __hip_bfloat16* orow = xh3 + (size_t)b * 4608;
        for (int k = tid; k < Ec; k += 256) {
            float v = emb[(size_t)tok * Ec + k];
            __hip_bfloat16 hi2 = __float2bfloat16(v);
            float lo = v - __bfloat162float(hi2);
            orow[k] = hi2;
            orow[Ec + k] = __float2bfloat16(lo);
            orow[2 * Ec + k] = hi2;
        }
    }
}

// ===========================================================================
// Hinge loss partial reduction; S layout [4][B][B]
// ===========================================================================
__global__ __launch_bounds__(256) void hinge_kernel(
    const float* __restrict__ S, const float* __restrict__ logp,
    float* __restrict__ partials, int Bn)
{
    int tid = threadIdx.x;
    int n = Bn * Bn;
    float acc = 0.0f;
    for (int idx = blockIdx.x * 256 + tid; idx < n; idx += gridDim.x * 256) {
        int j = idx & (Bn - 1);
        float s0 = S[idx];
        float l = fmaxf(0.0f, 1.0f - s0 + S[n + idx])
                + fmaxf(0.0f, 1.0f - s0 + S[2 * n + idx])
                + fmaxf(0.0f, 1.0f - s0 + S[3 * n + idx]);
        acc += l * logp[j];
    }
    __shared__ float sv[256];
    sv[tid] = acc;
    __syncthreads();
    for (int s = 128; s > 0; s >>= 1) {
        if (tid < s) sv[tid] += sv[tid + s];
        __syncthreads();
    }
    if (tid == 0) partials[blockIdx.x] = sv[0];
}

__global__ __launch_bounds__(256) void final_reduce_kernel(
    const float* __restrict__ partials, int np, float* __restrict__ out,
    float scale)
{
    int tid = threadIdx.x;
    float acc = 0.0f;
    for (int i = tid; i < np; i += 256) acc += partials[i];
    __shared__ float sv[256];
    sv[tid] = acc;
    __syncthreads();
    for (int s = 128; s > 0; s >>= 1) {
        if (tid < s) sv[tid] += sv[tid + s];
        __syncthreads();
    }
    if (tid == 0) out[0] = sv[0] * scale;
}

// ===========================================================================
extern "C" void kernel_launch(void* const* d_in, const int* in_sizes, int n_in,
                              void* d_out, int out_size, void* d_ws, size_t ws_size,
                              hipStream_t stream)
{
    (void)in_sizes; (void)n_in; (void)out_size; (void)ws_size;

    const float* target  = (const float*)d_in[0];
    const float* distr   = (const float*)d_in[1];
    const int*   start_t = (const int*)d_in[2];
    const float* W_aff = (const float*)d_in[4];
    const float* b_aff = (const float*)d_in[5];
    const float* emb_s = (const float*)d_in[6];
    const float* Wih_s = (const float*)d_in[7];
    const float* Whh_s = (const float*)d_in[8];
    const float* bih_s = (const float*)d_in[9];
    const float* bhh_s = (const float*)d_in[10];
    const float* Wp    = (const float*)d_in[11];
    const float* bp    = (const float*)d_in[12];
    const float* emb_r = (const float*)d_in[13];
    const float* Wih_r = (const float*)d_in[14];
    const float* Whh_r = (const float*)d_in[15];
    const float* bih_r = (const float*)d_in[16];
    const float* bhh_r = (const float*)d_in[17];
    const float* W_out = (const float*)d_in[18];
    const float* b_out = (const float*)d_in[19];

    dim3 blk(256);

    // ---------------- workspace layout ----------------
    char* b0 = (char*)d_ws;
    size_t off = 0;
    auto take = [&](size_t bytes) -> char* {
        char* p = b0 + off;
        off += (bytes + 511) & ~(size_t)511;
        return p;
    };
    const size_t MB = 1024 * 1024;
    __hip_bfloat16* WihWhh3 = (__hip_bfloat16*)take((size_t)G4c * 4608 * 2);
    __hip_bfloat16* Wp_b    = (__hip_bfloat16*)take((size_t)Vc * Hc * 2);
    __hip_bfloat16* WihWhh_r= (__hip_bfloat16*)take((size_t)G4c * 1536 * 2);
    __hip_bfloat16* W_out_b = (__hip_bfloat16*)take((size_t)NIFc * Hc * 2);
    __hip_bfloat16* xh3     = (__hip_bfloat16*)take((size_t)Bc * 4608 * 2);
    __hip_bfloat16* xh_r    = (__hip_bfloat16*)take((size_t)Bc * 1536 * 2);
    float* gates_p = (float*)take((size_t)2 * Bc * G4c * 4);  // split-K partials
    float* h_s    = (float*)take((size_t)Bc * Hc * 4);
    float* c_s    = (float*)take((size_t)Bc * Hc * 4);
    float* hr     = (float*)take((size_t)Bc * Hc * 4);
    float* cr     = (float*)take((size_t)Bc * Hc * 4);
    float* logp   = (float*)take(Bc * 4);
    int*   msg    = (int*)take((size_t)Lc * Bc * 4);
    float* parts  = (float*)take(1024 * 4);
    float* bias_s = (float*)take(G4c * 4);
    float* bias_r = (float*)take(G4c * 4);
    float* tilemax= (float*)take((size_t)Bc * TMLD * 4);
    char*  U      = take(48 * MB);

    // U sub-layout (phased reuse)
    __hip_bfloat16* target3 = (__hip_bfloat16*)U;                 // phase 1
    __hip_bfloat16* W_aff3  = (__hip_bfloat16*)(U + 13 * MB);     // phase 1
    float*          logits  = (float*)U;                          // phase 2 (40MB)
    __hip_bfloat16* A4b     = (__hip_bfloat16*)U;                 // phase 3
    float*          r_f     = (float*)(U + 17 * MB);              // phase 3
    __hip_bfloat16* r_b     = (__hip_bfloat16*)(U + 26 * MB);     // phase 3
    float*          S       = (float*)(U + 31 * MB);              // phase 3

    // ---- weight prep (per launch; one-time cost) ----
    split3_w_kernel<<<(G4c * Ec + 255) / 256, blk, 0, stream>>>(
        Wih_s, Ec, WihWhh3, 4608, 0, G4c, Ec);
    split3_w_kernel<<<(G4c * Hc + 255) / 256, blk, 0, stream>>>(
        Whh_s, Hc, WihWhh3, 4608, 1536, G4c, Hc);
    cast2d_kernel<<<(Vc * Hc + 255) / 256, blk, 0, stream>>>(
        Wp, Hc, Wp_b, Hc, 0, Vc, Hc);
    split3_a_kernel<<<(Bc * NIFc + 255) / 256, blk, 0, stream>>>(
        target, NIFc, target3, 6144, 0, Bc, NIFc);
    split3_w_kernel<<<(Hc * NIFc + 255) / 256, blk, 0, stream>>>(
        W_aff, NIFc, W_aff3, 6144, 0, Hc, NIFc);
    cast2d_kernel<<<(G4c * Ec + 255) / 256, blk, 0, stream>>>(
        Wih_r, Ec, WihWhh_r, 1536, 0, G4c, Ec);
    cast2d_kernel<<<(G4c * Hc + 255) / 256, blk, 0, stream>>>(
        Whh_r, Hc, WihWhh_r, 1536, Ec, G4c, Hc);
    cast2d_kernel<<<(NIFc * Hc + 255) / 256, blk, 0, stream>>>(
        W_out, Hc, W_out_b, Hc, 0, NIFc, Hc);
    add_vec_kernel<<<(G4c + 255) / 256, blk, 0, stream>>>(bih_s, bhh_s,
                                                          bias_s, G4c);
    add_vec_kernel<<<(G4c + 255) / 256, blk, 0, stream>>>(bih_r, bhh_r,
                                                          bias_r, G4c);

    // ---- sender init: h0 = target @ W_aff^T + b_aff (x3, split-K x2) ----
    gemm_bf16_sk2<<<dim3(Hc / GBN, Bc / GBM, 2), blk, 0, stream>>>(
        target3, 6144, W_aff3, 6144, gates_p, Bc, Hc, 3072);
    combine_h0_kernel<<<(Bc * Hc / 4 + 255) / 256, blk, 0, stream>>>(
        gates_p, gates_p + (size_t)Bc * Hc, b_aff, h_s, xh3);
    hipMemsetAsync(c_s, 0, (size_t)Bc * Hc * 4, stream);
    gather_split3_kernel<<<(Bc * Ec + 255) / 256, blk, 0, stream>>>(
        emb_s, Ec, start_t, 0, xh3, 4608, Bc);

    // ---- sender greedy decode ----
    for (int t = 0; t < Lc; ++t) {
        gemm_bf16_sk2<<<dim3(G4c / GBN, Bc / GBM, 2), blk, 0, stream>>>(
            xh3, 4608, WihWhh3, 4608, gates_p, Bc, G4c, 2304);
        lstm_fused_s<<<(Bc * Hc / 4 + 255) / 256, blk, 0, stream>>>(
            gates_p, gates_p + (size_t)Bc * G4c, bias_s, h_s, c_s, xh3);
        // approx logits = h_hi @ Wp_b^T + bp (plain bf16, K=1024) + tile maxima
        gemm_bf16_tn<<<dim3((Vc + GBN - 1) / GBN, Bc / GBM), blk, 0, stream>>>(
            xh3 + 1536, 4608, Wp_b, Hc, bp, logits, Bc, Vc, Hc, tilemax, TMLD);
        argmax_rescore_v2<<<Bc, blk, 0, stream>>>(
            logits, tilemax, h_s, Wp, bp, emb_s, msg + t * Bc, logp,
            (t < Lc - 1) ? xh3 : nullptr, (t == Lc - 1) ? 1 : 0);
    }

    // ---- receiver ----
    hipMemsetAsync(hr, 0, (size_t)Bc * Hc * 4, stream);
    hipMemsetAsync(cr, 0, (size_t)Bc * Hc * 4, stream);
    hipMemsetAsync(xh_r, 0, (size_t)Bc * 1536 * 2, stream);
    gather_cast_kernel<<<(Bc * Ec + 255) / 256, blk, 0, stream>>>(
        emb_r, Ec, msg, xh_r, 1536, 0, Bc);
    for (int t = 0; t < Lc; ++t) {
        gemm_bf16_sk2<<<dim3(G4c / GBN, Bc / GBM, 2), blk, 0, stream>>>(
            xh_r, 1536, WihWhh_r, 1536, gates_p, Bc, G4c, 768);
        lstm_fused_r<<<(Bc * Hc / 4 + 255) / 256, blk, 0, stream>>>(
            gates_p, gates_p + (size_t)Bc * G4c, bias_r, hr, cr, xh_r,
            emb_r, (t < Lc - 1) ? (msg + (t + 1) * Bc) : nullptr);
    }

    // ---- r = hr @ W_out^T + b_out ----
    gemm_bf16_tn<<<dim3(NIFc / GBN, Bc / GBM), blk, 0, stream>>>(
        xh_r + Ec, 1536, W_out_b, Hc, b_out, r_f, Bc, NIFc, Hc, nullptr, 0);

    // ---- similarities: [target; distractors] @ r^T in ONE GEMM ----
    cast2d_kernel<<<(Bc * NIFc + 255) / 256, blk, 0, stream>>>(
        target, NIFc, A4b, NIFc, 0, Bc, NIFc);
    cast2d_kernel<<<(NDc * Bc * NIFc + 255) / 256, blk, 0, stream>>>(
        distr, NIFc, A4b + (size_t)Bc * NIFc, NIFc, 0, NDc * Bc, NIFc);
    cast2d_kernel<<<(Bc * NIFc + 255) / 256, blk, 0, stream>>>(
        r_f, NIFc, r_b, NIFc, 0, Bc, NIFc);
    gemm_bf16_tn<<<dim3(Bc / GBN, 4 * Bc / GBM), blk, 0, stream>>>(
        A4b, NIFc, r_b, NIFc, nullptr, S, 4 * Bc, Bc, NIFc, nullptr, 0);

    hinge_kernel<<<1024, blk, 0, stream>>>(S, logp, parts, Bc);
    final_reduce_kernel<<<1, blk, 0, stream>>>(
        parts, 1024, (float*)d_out, -1.0f / ((float)Bc * (float)Bc));
}

// Round 5
// 4789.963 us; speedup vs baseline: 7.5893x; 1.6055x over previous
//
#include <hip/hip_runtime.h>
#include <hip/hip_bf16.h>
#include <cstdint>
#include <cstddef>

// Problem constants (fixed by setup_inputs in the reference)
#define Bc   1024
#define NIFc 2048
#define Vc   10000
#define Ec   512
#define Hc   1024
#define Lc   32
#define NDc  3
#define G4c  4096   // 4*H
#define NTv  79     // ceil(V/128) logits tiles
#define TMLD 80     // tilemax row stride

typedef __attribute__((ext_vector_type(4))) float f32x4;
typedef __attribute__((ext_vector_type(8))) short s16x8;
typedef __attribute__((ext_vector_type(4))) short s16x4;

// ===========================================================================
// bf16 MFMA GEMM body:  C[M,N] = A[M,K] @ W[N,K]^T (+ bias[N])
// 128x128 tile, BK=64, 256 thr (4 waves 2x2), 4x4 MFMA 16x16x32/wave.
// global_load_lds w=16 staging, XOR-swizzled LDS chunks (2-way alias = free).
// Optional epilogue: per-row max over this block's 128 cols -> tile_max.
// ===========================================================================
#define GBM 128
#define GBN 128
#define GBK 64

__device__ __forceinline__ void gld_lds16(void* lds, const void* g) {
    __builtin_amdgcn_global_load_lds(
        (const __attribute__((address_space(1))) unsigned int*)g,
        (__attribute__((address_space(3))) unsigned int*)lds,
        16, 0, 0);
}

__device__ __forceinline__ void gemm_body(
    const __hip_bfloat16* __restrict__ A, int lda,
    const __hip_bfloat16* __restrict__ W, int ldw,
    const float* __restrict__ bias, float* __restrict__ C,
    int M, int N, int K, int bx, int by,
    float* __restrict__ tile_max, int tmld)
{
    __shared__ __align__(16) __hip_bfloat16 As[GBM * GBK];
    __shared__ __align__(16) __hip_bfloat16 Ws[GBN * GBK];
    __shared__ float smax[GBM];

    const int tid  = threadIdx.x;
    const int lane = tid & 63;
    const int wave = tid >> 6;
    const int m0 = by * GBM;
    const int n0 = bx * GBN;

    const __hip_bfloat16* ag[4];
    const __hip_bfloat16* wg[4];
    #pragma unroll
    for (int r = 0; r < 4; ++r) {
        int p = r * 256 + tid;
        int m = p >> 3;
        int q = (p & 7) ^ (m & 7);
        ag[r] = A + (size_t)(m0 + m) * lda + q * 8;
        int wn = n0 + m; if (wn >= N) wn = N - 1;
        wg[r] = W + (size_t)wn * ldw + q * 8;
    }

    f32x4 acc[4][4];
    #pragma unroll
    for (int i = 0; i < 4; ++i)
        #pragma unroll
        for (int j = 0; j < 4; ++j)
            acc[i][j] = (f32x4)(0.0f);

    const int hm = (wave & 1) << 6;
    const int hn = (wave >> 1) << 6;
    const int lm = lane & 15;
    const int quad = lane >> 4;

    const int nk = K >> 6;
    for (int kt = 0; kt < nk; ++kt) {
        __syncthreads();
        #pragma unroll
        for (int r = 0; r < 4; ++r) {
            int ldsbase = (r * 256 + wave * 64) * 8;
            gld_lds16(As + ldsbase, ag[r]);
            gld_lds16(Ws + ldsbase, wg[r]);
            ag[r] += GBK;
            wg[r] += GBK;
        }
        __syncthreads();
        #pragma unroll
        for (int c = 0; c < 2; ++c) {
            s16x8 af[4], wf[4];
            int q = c * 4 + quad;
            #pragma unroll
            for (int i = 0; i < 4; ++i) {
                int m = hm + i * 16 + lm;
                af[i] = *(const s16x8*)(As + ((m << 3) + (q ^ (m & 7))) * 8);
                int n = hn + i * 16 + lm;
                wf[i] = *(const s16x8*)(Ws + ((n << 3) + (q ^ (n & 7))) * 8);
            }
            #pragma unroll
            for (int i = 0; i < 4; ++i)
                #pragma unroll
                for (int j = 0; j < 4; ++j)
                    acc[i][j] = __builtin_amdgcn_mfma_f32_16x16x32_bf16(
                        af[i], wf[j], acc[i][j], 0, 0, 0);
        }
    }

    // epilogue: C/D layout col=lane&15, row=quad*4+reg
    float rowmax[4][4];
    #pragma unroll
    for (int i = 0; i < 4; ++i)
        #pragma unroll
        for (int rr = 0; rr < 4; ++rr)
            rowmax[i][rr] = -__builtin_inff();

    #pragma unroll
    for (int i = 0; i < 4; ++i) {
        int mbase = m0 + hm + i * 16 + quad * 4;
        #pragma unroll
        for (int j = 0; j < 4; ++j) {
            int n = n0 + hn + j * 16 + lm;
            if (n < N) {
                float bv = bias ? bias[n] : 0.0f;
                #pragma unroll
                for (int rr = 0; rr < 4; ++rr) {
                    float v = acc[i][j][rr] + bv;
                    C[(size_t)(mbase + rr) * N + n] = v;
                    rowmax[i][rr] = fmaxf(rowmax[i][rr], v);
                }
            }
        }
    }

    if (tile_max) {
        #pragma unroll
        for (int i = 0; i < 4; ++i)
            #pragma unroll
            for (int rr = 0; rr < 4; ++rr) {
                float v = rowmax[i][rr];
                v = fmaxf(v, __shfl_xor(v, 1));
                v = fmaxf(v, __shfl_xor(v, 2));
                v = fmaxf(v, __shfl_xor(v, 4));
                v = fmaxf(v, __shfl_xor(v, 8));
                rowmax[i][rr] = v;
            }
        __syncthreads();
        if (hn == 0 && lm == 0) {
            #pragma unroll
            for (int i = 0; i < 4; ++i)
                #pragma unroll
                for (int rr = 0; rr < 4; ++rr)
                    smax[hm + i * 16 + quad * 4 + rr] = rowmax[i][rr];
        }
        __syncthreads();
        if (hn == 64 && lm == 0) {
            #pragma unroll
            for (int i = 0; i < 4; ++i)
                #pragma unroll
                for (int rr = 0; rr < 4; ++rr) {
                    int r = hm + i * 16 + quad * 4 + rr;
                    smax[r] = fmaxf(smax[r], rowmax[i][rr]);
                }
        }
        __syncthreads();
        if (tid < GBM)
            tile_max[(size_t)(m0 + tid) * tmld + bx] = smax[tid];
    }
}

__global__ __launch_bounds__(256) void gemm_bf16_tn(
    const __hip_bfloat16* __restrict__ A, int lda,
    const __hip_bfloat16* __restrict__ W, int ldw,
    const float* __restrict__ bias, float* __restrict__ C,
    int M, int N, int K, float* __restrict__ tile_max, int tmld)
{
    gemm_body(A, lda, W, ldw, bias, C, M, N, K, blockIdx.x, blockIdx.y,
              tile_max, tmld);
}

// split-K x2: blockIdx.z selects K-half; fp32 partials, no bias.
__global__ __launch_bounds__(256) void gemm_bf16_sk2(
    const __hip_bfloat16* __restrict__ A, int lda,
    const __hip_bfloat16* __restrict__ W, int ldw,
    float* __restrict__ Cpart, int M, int N, int Ksub)
{
    int z = blockIdx.z;
    gemm_body(A + (size_t)z * Ksub, lda, W + (size_t)z * Ksub, ldw, nullptr,
              Cpart + (size_t)z * M * N, M, N, Ksub, blockIdx.x, blockIdx.y,
              nullptr, 0);
}

// ===========================================================================
// Cast / split kernels.  x3 split: A3=[A_hi|A_lo|A_hi], W3=[W_hi|W_hi|W_lo]
// ===========================================================================
__global__ __launch_bounds__(256) void split3_a_kernel(
    const float* __restrict__ in, int ldin,
    __hip_bfloat16* __restrict__ out, int ldo, int coff, int M, int K)
{
    int i = blockIdx.x * 256 + threadIdx.x;
    if (i >= M * K) return;
    int m = i / K, k = i - m * K;
    float v = in[(size_t)m * ldin + k];
    __hip_bfloat16 hi = __float2bfloat16(v);
    float lo = v - __bfloat162float(hi);
    __hip_bfloat16* row = out + (size_t)m * ldo + coff;
    row[k] = hi;
    row[K + k] = __float2bfloat16(lo);
    row[2 * K + k] = hi;
}

__global__ __launch_bounds__(256) void split3_w_kernel(
    const float* __restrict__ in, int ldin,
    __hip_bfloat16* __restrict__ out, int ldo, int coff, int M, int K)
{
    int i = blockIdx.x * 256 + threadIdx.x;
    if (i >= M * K) return;
    int m = i / K, k = i - m * K;
    float v = in[(size_t)m * ldin + k];
    __hip_bfloat16 hi = __float2bfloat16(v);
    float lo = v - __bfloat162float(hi);
    __hip_bfloat16* row = out + (size_t)m * ldo + coff;
    row[k] = hi;
    row[K + k] = hi;
    row[2 * K + k] = __float2bfloat16(lo);
}

__global__ __launch_bounds__(256) void cast2d_kernel(
    const float* __restrict__ in, int ldin,
    __hip_bfloat16* __restrict__ out, int ldo, int coff, int M, int K)
{
    int i = blockIdx.x * 256 + threadIdx.x;
    if (i >= M * K) return;
    int m = i / K, k = i - m * K;
    out[(size_t)m * ldo + coff + k] = __float2bfloat16(in[(size_t)m * ldin + k]);
}

__global__ __launch_bounds__(256) void gather_split3_kernel(
    const float* __restrict__ emb, int E, const int* __restrict__ idx,
    int stride, __hip_bfloat16* __restrict__ out, int ldo, int Brows)
{
    int i = blockIdx.x * 256 + threadIdx.x;
    if (i >= Brows * E) return;
    int b = i / E, k = i - b * E;
    float v = emb[(size_t)idx[b * stride] * E + k];
    __hip_bfloat16 hi = __float2bfloat16(v);
    float lo = v - __bfloat162float(hi);
    __hip_bfloat16* row = out + (size_t)b * ldo;
    row[k] = hi;
    row[E + k] = __float2bfloat16(lo);
    row[2 * E + k] = hi;
}

__global__ __launch_bounds__(256) void gather_cast_kernel(
    const float* __restrict__ emb, int E, const int* __restrict__ idx,
    __hip_bfloat16* __restrict__ out, int ldo, int coff, int Brows)
{
    int i = blockIdx.x * 256 + threadIdx.x;
    if (i >= Brows * E) return;
    int b = i / E, k = i - b * E;
    out[(size_t)b * ldo + coff + k] =
        __float2bfloat16(emb[(size_t)idx[b] * E + k]);
}

__global__ __launch_bounds__(256) void add_vec_kernel(
    const float* __restrict__ a, const float* __restrict__ b,
    float* __restrict__ o, int n)
{
    int i = blockIdx.x * 256 + threadIdx.x;
    if (i < n) o[i] = a[i] + b[i];
}

// ===========================================================================
// Vectorized LSTM pointwise kernels (float4 loads, 8B bf16 stores)
// ===========================================================================
__device__ __forceinline__ short bf16bits(float x) {
    __hip_bfloat16 t = __float2bfloat16(x);
    return *reinterpret_cast<short*>(&t);
}

__global__ __launch_bounds__(256) void lstm_fused_s(
    const float* __restrict__ gp0, const float* __restrict__ gp1,
    const float* __restrict__ bias, float* __restrict__ h,
    float* __restrict__ c, __hip_bfloat16* __restrict__ xh3)
{
    int i = blockIdx.x * 256 + threadIdx.x;      // over Bc*Hc/4
    if (i >= Bc * Hc / 4) return;
    int b = i >> 8;
    int j = (i & 255) * 4;
    size_t g0 = (size_t)b * G4c + j;
    f32x4 gi = *(const f32x4*)(gp0 + g0) + *(const f32x4*)(gp1 + g0)
             + *(const f32x4*)(bias + j);
    f32x4 gf = *(const f32x4*)(gp0 + g0 + Hc) + *(const f32x4*)(gp1 + g0 + Hc)
             + *(const f32x4*)(bias + Hc + j);
    f32x4 gg = *(const f32x4*)(gp0 + g0 + 2 * Hc) + *(const f32x4*)(gp1 + g0 + 2 * Hc)
             + *(const f32x4*)(bias + 2 * Hc + j);
    f32x4 go = *(const f32x4*)(gp0 + g0 + 3 * Hc) + *(const f32x4*)(gp1 + g0 + 3 * Hc)
             + *(const f32x4*)(bias + 3 * Hc + j);
    size_t hix = (size_t)b * Hc + j;
    f32x4 cv = *(const f32x4*)(c + hix);
    f32x4 cn, hv;
    s16x4 hi4, lo4;
    #pragma unroll
    for (int k = 0; k < 4; ++k) {
        float si = 1.0f / (1.0f + expf(-gi[k]));
        float sf = 1.0f / (1.0f + expf(-gf[k]));
        float so = 1.0f / (1.0f + expf(-go[k]));
        float cc = sf * cv[k] + si * tanhf(gg[k]);
        cn[k] = cc;
        float hh = so * tanhf(cc);
        hv[k] = hh;
        hi4[k] = bf16bits(hh);
        lo4[k] = bf16bits(hh - __bfloat162float(__float2bfloat16(hh)));
    }
    *(f32x4*)(c + hix) = cn;
    *(f32x4*)(h + hix) = hv;
    __hip_bfloat16* row = xh3 + (size_t)b * 4608 + 1536;
    *(s16x4*)(row + j) = hi4;
    *(s16x4*)(row + Hc + j) = lo4;
    *(s16x4*)(row + 2 * Hc + j) = hi4;
}

__global__ __launch_bounds__(256) void combine_h0_kernel(
    const float* __restrict__ p0, const float* __restrict__ p1,
    const float* __restrict__ bias, float* __restrict__ h,
    __hip_bfloat16* __restrict__ xh3)
{
    int i = blockIdx.x * 256 + threadIdx.x;
    if (i >= Bc * Hc / 4) return;
    int b = i >> 8;
    int j = (i & 255) * 4;
    size_t ix = (size_t)b * Hc + j;
    f32x4 v = *(const f32x4*)(p0 + ix) + *(const f32x4*)(p1 + ix)
            + *(const f32x4*)(bias + j);
    *(f32x4*)(h + ix) = v;
    s16x4 hi4, lo4;
    #pragma unroll
    for (int k = 0; k < 4; ++k) {
        hi4[k] = bf16bits(v[k]);
        lo4[k] = bf16bits(v[k] - __bfloat162float(__float2bfloat16(v[k])));
    }
    __hip_bfloat16* row = xh3 + (size_t)b * 4608 + 1536;
    *(s16x4*)(row + j) = hi4;
    *(s16x4*)(row + Hc + j) = lo4;
    *(s16x4*)(row + 2 * Hc + j) = hi4;
}

__global__ __launch_bounds__(256) void lstm_fused_r(
    const float* __restrict__ gp0, const float* __restrict__ gp1,
    const float* __restrict__ bias, float* __restrict__ h,
    float* __restrict__ c, __hip_bfloat16* __restrict__ xh_r,
    const float* __restrict__ emb, const int* __restrict__ msg_next)
{
    int i = blockIdx.x * 256 + threadIdx.x;
    if (i >= Bc * Hc / 4) return;
    int b = i >> 8;
    int j = (i & 255) * 4;
    size_t g0 = (size_t)b * G4c + j;
    f32x4 gi = *(const f32x4*)(gp0 + g0) + *(const f32x4*)(gp1 + g0)
             + *(const f32x4*)(bias + j);
    f32x4 gf = *(const f32x4*)(gp0 + g0 + Hc) + *(const f32x4*)(gp1 + g0 + Hc)
             + *(const f32x4*)(bias + Hc + j);
    f32x4 gg = *(const f32x4*)(gp0 + g0 + 2 * Hc) + *(const f32x4*)(gp1 + g0 + 2 * Hc)
             + *(const f32x4*)(bias + 2 * Hc + j);
    f32x4 go = *(const f32x4*)(gp0 + g0 + 3 * Hc) + *(const f32x4*)(gp1 + g0 + 3 * Hc)
             + *(const f32x4*)(bias + 3 * Hc + j);
    size_t hix = (size_t)b * Hc + j;
    f32x4 cv = *(const f32x4*)(c + hix);
    f32x4 cn, hv;
    s16x4 hb4;
    #pragma unroll
    for (int k = 0; k < 4; ++k) {
        float si = 1.0f / (1.0f + expf(-gi[k]));
        float sf = 1.0f / (1.0f + expf(-gf[k]));
        float so = 1.0f / (1.0f + expf(-go[k]));
        float cc = sf * cv[k] + si * tanhf(gg[k]);
        cn[k] = cc;
        float hh = so * tanhf(cc);
        hv[k] = hh;
        hb4[k] = bf16bits(hh);
    }
    *(f32x4*)(c + hix) = cn;
    *(f32x4*)(h + hix) = hv;
    *(s16x4*)(xh_r + (size_t)b * 1536 + Ec + j) = hb4;
    if (msg_next && j < Ec) {
        int tok = msg_next[b];
        f32x4 e = *(const f32x4*)(emb + (size_t)tok * Ec + j);
        s16x4 eb;
        #pragma unroll
        for (int k = 0; k < 4; ++k) eb[k] = bf16bits(e[k]);
        *(s16x4*)(xh_r + (size_t)b * 1536 + j) = eb;
    }
}

// ===========================================================================
// argmax v3: tile maxima -> approx max m + per-row spread (m - mean(tmax)) ->
// spread-PROPORTIONAL delta (bf16 logit error scales with row sigma) ->
// scan only qualifying tiles -> wave-parallel exact fp32 rescore (shuffle
// butterfly, no barriers in the loop) -> token + optional logp + next-token
// split3 gather. One block (256 thr) per batch row.
// ===========================================================================
__global__ __launch_bounds__(256) void argmax_rescore_v3(
    const float* __restrict__ logits, const float* __restrict__ tmax,
    const float* __restrict__ h, const float* __restrict__ Wp,
    const float* __restrict__ bp, const float* __restrict__ emb,
    int* __restrict__ msg_t, float* __restrict__ logp,
    __hip_bfloat16* __restrict__ xh3, int want_logp)
{
    const int b = blockIdx.x;
    const int tid = threadIdx.x;
    const int lane = tid & 63;
    const int wave = tid >> 6;
    const float* row = logits + (size_t)b * Vc;

    __shared__ float stm[128];
    __shared__ float redm[256];
    __shared__ float reds[256];
    __shared__ int   qt[32];
    __shared__ int   nq, cnt;
    __shared__ int   cand[64];
    __shared__ float score[64];
    __shared__ float sbestv;
    __shared__ int   sbestj;

    float tv = (tid < NTv) ? tmax[(size_t)b * TMLD + tid] : -__builtin_inff();
    if (tid < 128) stm[tid] = tv;
    redm[tid] = tv;
    reds[tid] = (tid < NTv) ? tv : 0.0f;
    if (tid == 0) { nq = 0; cnt = 0; }
    __syncthreads();
    #pragma unroll
    for (int s = 128; s > 0; s >>= 1) {
        if (tid < s) {
            redm[tid] = fmaxf(redm[tid], redm[tid + s]);
            reds[tid] += reds[tid + s];
        }
        __syncthreads();
    }
    const float m = redm[0];
    const float spread = m - reds[0] * (1.0f / NTv);   // ~1.3 sigma_logit
    const float delta = 0.08f * spread + 1e-6f * (1.0f + fabsf(m));

    // qualifying tiles
    if (tid < NTv && stm[tid] >= m - delta) {
        int k = atomicAdd(&nq, 1);
        if (k < 32) qt[k] = tid;
    }
    __syncthreads();
    int nqt = nq < 32 ? nq : 32;

    // candidate collection: 2 tiles per iteration (256 threads)
    for (int qi = 0; qi < nqt; qi += 2) {
        int ti = qi + (tid >> 7);
        if (ti < nqt) {
            int j = qt[ti] * 128 + (tid & 127);
            if (j < Vc) {
                float v = row[j];
                if (v >= m - delta) {
                    int k = atomicAdd(&cnt, 1);
                    if (k < 64) cand[k] = j;
                }
            }
        }
    }
    __syncthreads();
    int nc = cnt < 64 ? cnt : 64;

    // wave-parallel exact fp32 rescore (shuffle butterfly per wave)
    const float* hrow = h + (size_t)b * Hc;
    for (int cix = wave; cix < nc; cix += 4) {
        int j = cand[cix];
        const float* wrow = Wp + (size_t)j * Hc;
        float part = 0.0f;
        #pragma unroll
        for (int kk = 0; kk < 4; ++kk) {
            int k = kk * 256 + lane * 4;
            f32x4 hv = *(const f32x4*)(hrow + k);
            f32x4 wv = *(const f32x4*)(wrow + k);
            part = fmaf(hv.x, wv.x, part);
            part = fmaf(hv.y, wv.y, part);
            part = fmaf(hv.z, wv.z, part);
            part = fmaf(hv.w, wv.w, part);
        }
        #pragma unroll
        for (int off = 1; off < 64; off <<= 1)
            part += __shfl_xor(part, off);
        if (lane == 0) score[cix] = part + bp[j];
    }
    __syncthreads();
    if (tid == 0) {
        float bv = -__builtin_inff();
        int bj = 0x7fffffff;
        for (int cix = 0; cix < nc; ++cix) {
            float v = score[cix];
            int j = cand[cix];
            if (v > bv || (v == bv && j < bj)) { bv = v; bj = j; }
        }
        sbestv = bv;
        sbestj = bj;
        msg_t[b] = bj;
    }
    __syncthreads();
    const int bestj = sbestj;

    if (want_logp) {
        float s = 0.0f;
        const f32x4* row4 = (const f32x4*)row;       // Vc % 4 == 0
        for (int j = tid; j < Vc / 4; j += 256) {
            f32x4 v = row4[j];
            s += expf(v.x - m) + expf(v.y - m) + expf(v.z - m) + expf(v.w - m);
        }
        redm[tid] = s;
        __syncthreads();
        #pragma unroll
        for (int st = 128; st > 0; st >>= 1) {
            if (tid < st) redm[tid] += redm[tid + st];
            __syncthreads();
        }
        if (tid == 0) logp[b] = sbestv - (m + logf(redm[0]));
    }

    // next-token embedding gather, split3 (float4), into xh3 x-region
    if (xh3 && tid < 128) {
        int k = tid * 4;
        f32x4 e = *(const f32x4*)(emb + (size_t)bestj * Ec + k);
        s16x4 hi4, lo4;
        #pragma unroll
        for (int kk = 0; kk < 4; ++kk) {
            hi4[kk] = bf16bits(e[kk]);
            lo4[kk] = bf16bits(e[kk] - __bfloat162float(__float2bfloat16(e[kk])));
        }
        __hip_bfloat16* orow = xh3 + (size_t)b * 4608;
        *(s16x4*)(orow + k) = hi4;
        *(s16x4*)(orow + Ec + k) = lo4;
        *(s16x4*)(orow + 2 * Ec + k) = hi4;
    }
}

// ===========================================================================
// Hinge loss partial reduction; S layout [4][B][B]
// ===========================================================================
__global__ __launch_bounds__(256) void hinge_kernel(
    const float* __restrict__ S, const float* __restrict__ logp,
    float* __restrict__ partials, int Bn)
{
    int tid = threadIdx.x;
    int n = Bn * Bn;
    float acc = 0.0f;
    for (int idx = blockIdx.x * 256 + tid; idx < n; idx += gridDim.x * 256) {
        int j = idx & (Bn - 1);
        float s0 = S[idx];
        float l = fmaxf(0.0f, 1.0f - s0 + S[n + idx])
                + fmaxf(0.0f, 1.0f - s0 + S[2 * n + idx])
                + fmaxf(0.0f, 1.0f - s0 + S[3 * n + idx]);
        acc += l * logp[j];
    }
    __shared__ float sv[256];
    sv[tid] = acc;
    __syncthreads();
    for (int s = 128; s > 0; s >>= 1) {
        if (tid < s) sv[tid] += sv[tid + s];
        __syncthreads();
    }
    if (tid == 0) partials[blockIdx.x] = sv[0];
}

__global__ __launch_bounds__(256) void final_reduce_kernel(
    const float* __restrict__ partials, int np, float* __restrict__ out,
    float scale)
{
    int tid = threadIdx.x;
    float acc = 0.0f;
    for (int i = tid; i < np; i += 256) acc += partials[i];
    __shared__ float sv[256];
    sv[tid] = acc;
    __syncthreads();
    for (int s = 128; s > 0; s >>= 1) {
        if (tid < s) sv[tid] += sv[tid + s];
        __syncthreads();
    }
    if (tid == 0) out[0] = sv[0] * scale;
}

// ===========================================================================
extern "C" void kernel_launch(void* const* d_in, const int* in_sizes, int n_in,
                              void* d_out, int out_size, void* d_ws, size_t ws_size,
                              hipStream_t stream)
{
    (void)in_sizes; (void)n_in; (void)out_size; (void)ws_size;

    const float* target  = (const float*)d_in[0];
    const float* distr   = (const float*)d_in[1];
    const int*   start_t = (const int*)d_in[2];
    const float* W_aff = (const float*)d_in[4];
    const float* b_aff = (const float*)d_in[5];
    const float* emb_s = (const float*)d_in[6];
    const float* Wih_s = (const float*)d_in[7];
    const float* Whh_s = (const float*)d_in[8];
    const float* bih_s = (const float*)d_in[9];
    const float* bhh_s = (const float*)d_in[10];
    const float* Wp    = (const float*)d_in[11];
    const float* bp    = (const float*)d_in[12];
    const float* emb_r = (const float*)d_in[13];
    const float* Wih_r = (const float*)d_in[14];
    const float* Whh_r = (const float*)d_in[15];
    const float* bih_r = (const float*)d_in[16];
    const float* bhh_r = (const float*)d_in[17];
    const float* W_out = (const float*)d_in[18];
    const float* b_out = (const float*)d_in[19];

    dim3 blk(256);

    // ---------------- workspace layout ----------------
    char* b0 = (char*)d_ws;
    size_t off = 0;
    auto take = [&](size_t bytes) -> char* {
        char* p = b0 + off;
        off += (bytes + 511) & ~(size_t)511;
        return p;
    };
    const size_t MB = 1024 * 1024;
    __hip_bfloat16* WihWhh3 = (__hip_bfloat16*)take((size_t)G4c * 4608 * 2);
    __hip_bfloat16* Wp_b    = (__hip_bfloat16*)take((size_t)Vc * Hc * 2);
    __hip_bfloat16* WihWhh_r= (__hip_bfloat16*)take((size_t)G4c * 1536 * 2);
    __hip_bfloat16* W_out_b = (__hip_bfloat16*)take((size_t)NIFc * Hc * 2);
    __hip_bfloat16* xh3     = (__hip_bfloat16*)take((size_t)Bc * 4608 * 2);
    __hip_bfloat16* xh_r    = (__hip_bfloat16*)take((size_t)Bc * 1536 * 2);
    float* gates_p = (float*)take((size_t)2 * Bc * G4c * 4);  // split-K partials
    float* h_s    = (float*)take((size_t)Bc * Hc * 4);
    float* c_s    = (float*)take((size_t)Bc * Hc * 4);
    float* hr     = (float*)take((size_t)Bc * Hc * 4);
    float* cr     = (float*)take((size_t)Bc * Hc * 4);
    float* logp   = (float*)take(Bc * 4);
    int*   msg    = (int*)take((size_t)Lc * Bc * 4);
    float* parts  = (float*)take(1024 * 4);
    float* bias_s = (float*)take(G4c * 4);
    float* bias_r = (float*)take(G4c * 4);
    float* tilemax= (float*)take((size_t)Bc * TMLD * 4);
    char*  U      = take(48 * MB);

    // U sub-layout (phased reuse)
    __hip_bfloat16* target3 = (__hip_bfloat16*)U;                 // phase 1
    __hip_bfloat16* W_aff3  = (__hip_bfloat16*)(U + 13 * MB);     // phase 1
    float*          logits  = (float*)U;                          // phase 2 (40MB)
    __hip_bfloat16* A4b     = (__hip_bfloat16*)U;                 // phase 3
    float*          r_f     = (float*)(U + 17 * MB);              // phase 3
    __hip_bfloat16* r_b     = (__hip_bfloat16*)(U + 26 * MB);     // phase 3
    float*          S       = (float*)(U + 31 * MB);              // phase 3

    // ---- weight prep (per launch; one-time cost) ----
    split3_w_kernel<<<(G4c * Ec + 255) / 256, blk, 0, stream>>>(
        Wih_s, Ec, WihWhh3, 4608, 0, G4c, Ec);
    split3_w_kernel<<<(G4c * Hc + 255) / 256, blk, 0, stream>>>(
        Whh_s, Hc, WihWhh3, 4608, 1536, G4c, Hc);
    cast2d_kernel<<<(Vc * Hc + 255) / 256, blk, 0, stream>>>(
        Wp, Hc, Wp_b, Hc, 0, Vc, Hc);
    split3_a_kernel<<<(Bc * NIFc + 255) / 256, blk, 0, stream>>>(
        target, NIFc, target3, 6144, 0, Bc, NIFc);
    split3_w_kernel<<<(Hc * NIFc + 255) / 256, blk, 0, stream>>>(
        W_aff, NIFc, W_aff3, 6144, 0, Hc, NIFc);
    cast2d_kernel<<<(G4c * Ec + 255) / 256, blk, 0, stream>>>(
        Wih_r, Ec, WihWhh_r, 1536, 0, G4c, Ec);
    cast2d_kernel<<<(G4c * Hc + 255) / 256, blk, 0, stream>>>(
        Whh_r, Hc, WihWhh_r, 1536, Ec, G4c, Hc);
    cast2d_kernel<<<(NIFc * Hc + 255) / 256, blk, 0, stream>>>(
        W_out, Hc, W_out_b, Hc, 0, NIFc, Hc);
    add_vec_kernel<<<(G4c + 255) / 256, blk, 0, stream>>>(bih_s, bhh_s,
                                                          bias_s, G4c);
    add_vec_kernel<<<(G4c + 255) / 256, blk, 0, stream>>>(bih_r, bhh_r,
                                                          bias_r, G4c);

    // ---- sender init: h0 = target @ W_aff^T + b_aff (x3, split-K x2) ----
    gemm_bf16_sk2<<<dim3(Hc / GBN, Bc / GBM, 2), blk, 0, stream>>>(
        target3, 6144, W_aff3, 6144, gates_p, Bc, Hc, 3072);
    combine_h0_kernel<<<(Bc * Hc / 4 + 255) / 256, blk, 0, stream>>>(
        gates_p, gates_p + (size_t)Bc * Hc, b_aff, h_s, xh3);
    hipMemsetAsync(c_s, 0, (size_t)Bc * Hc * 4, stream);
    gather_split3_kernel<<<(Bc * Ec + 255) / 256, blk, 0, stream>>>(
        emb_s, Ec, start_t, 0, xh3, 4608, Bc);

    // ---- sender greedy decode ----
    for (int t = 0; t < Lc; ++t) {
        gemm_bf16_sk2<<<dim3(G4c / GBN, Bc / GBM, 2), blk, 0, stream>>>(
            xh3, 4608, WihWhh3, 4608, gates_p, Bc, G4c, 2304);
        lstm_fused_s<<<(Bc * Hc / 4 + 255) / 256, blk, 0, stream>>>(
            gates_p, gates_p + (size_t)Bc * G4c, bias_s, h_s, c_s, xh3);
        // approx logits = h_hi @ Wp_b^T + bp (plain bf16, K=1024) + tile maxima
        gemm_bf16_tn<<<dim3((Vc + GBN - 1) / GBN, Bc / GBM), blk, 0, stream>>>(
            xh3 + 1536, 4608, Wp_b, Hc, bp, logits, Bc, Vc, Hc, tilemax, TMLD);
        argmax_rescore_v3<<<Bc, blk, 0, stream>>>(
            logits, tilemax, h_s, Wp, bp, emb_s, msg + t * Bc, logp,
            (t < Lc - 1) ? xh3 : nullptr, (t == Lc - 1) ? 1 : 0);
    }

    // ---- receiver ----
    hipMemsetAsync(hr, 0, (size_t)Bc * Hc * 4, stream);
    hipMemsetAsync(cr, 0, (size_t)Bc * Hc * 4, stream);
    hipMemsetAsync(xh_r, 0, (size_t)Bc * 1536 * 2, stream);
    gather_cast_kernel<<<(Bc * Ec + 255) / 256, blk, 0, stream>>>(
        emb_r, Ec, msg, xh_r, 1536, 0, Bc);
    for (int t = 0; t < Lc; ++t) {
        gemm_bf16_sk2<<<dim3(G4c / GBN, Bc / GBM, 2), blk, 0, stream>>>(
            xh_r, 1536, WihWhh_r, 1536, gates_p, Bc, G4c, 768);
        lstm_fused_r<<<(Bc * Hc / 4 + 255) / 256, blk, 0, stream>>>(
            gates_p, gates_p + (size_t)Bc * G4c, bias_r, hr, cr, xh_r,
            emb_r, (t < Lc - 1) ? (msg + (t + 1) * Bc) : nullptr);
    }

    // ---- r = hr @ W_out^T + b_out ----
    gemm_bf16_tn<<<dim3(NIFc / GBN, Bc / GBM), blk, 0, stream>>>(
        xh_r + Ec, 1536, W_out_b, Hc, b_out, r_f, Bc, NIFc, Hc, nullptr, 0);

    // ---- similarities: [target; distractors] @ r^T in ONE GEMM ----
    cast2d_kernel<<<(Bc * NIFc + 255) / 256, blk, 0, stream>>>(
        target, NIFc, A4b, NIFc, 0, Bc, NIFc);
    cast2d_kernel<<<(NDc * Bc * NIFc + 255) / 256, blk, 0, stream>>>(
        distr, NIFc, A4b + (size_t)Bc * NIFc, NIFc, 0, NDc * Bc, NIFc);
    cast2d_kernel<<<(Bc * NIFc + 255) / 256, blk, 0, stream>>>(
        r_f, NIFc, r_b, NIFc, 0, Bc, NIFc);
    gemm_bf16_tn<<<dim3(Bc / GBN, 4 * Bc / GBM), blk, 0, stream>>>(
        A4b, NIFc, r_b, NIFc, nullptr, S, 4 * Bc, Bc, NIFc, nullptr, 0);

    hinge_kernel<<<1024, blk, 0, stream>>>(S, logp, parts, Bc);
    final_reduce_kernel<<<1, blk, 0, stream>>>(
        parts, 1024, (float*)d_out, -1.0f / ((float)Bc * (float)Bc));
}